// Round 4
// baseline (33726.340 us; speedup 1.0000x reference)
//
#include <hip/hip_runtime.h>
#include <hip/hip_bf16.h>
#include <cstdint>
#include <cstddef>

// All reference inputs are float32 (setup_inputs uses jnp.float32 throughout).
// Misreading them as bf16 was the round-0..3 failure: fp32 buffers viewed as
// bf16 pairs produce deterministic garbage -> BN collapse -> identical wrong
// loss across independent conv implementations.

// ---------------------------------------------------------------------------
// v2 conv stack: correctness-first.
// NCHW fp32 activations; weights OIHW fp32. Conv 3x3 stride-1 SAME zero-pad,
// cross-correlation. Per layer: (1) stats pass (sum/sumsq per (group,oc),
// f64 atomics); (2) apply pass (conv, y=a*scale+shift, relu, 2x2 maxpool).
// Support (n<192) and query (n>=192) get separate BN statistics groups.
// ---------------------------------------------------------------------------

template<int IC, int OC, int H>
__global__ __launch_bounds__(256)
void conv_stats_v2(const float* __restrict__ inA, const float* __restrict__ inB,
                   int nSplit, const float* __restrict__ W,
                   double* __restrict__ stats, int nSupport)
{
  const int n = blockIdx.z, oc = blockIdx.y, tid = threadIdx.x;
  const float* in = (n < nSplit) ? inA + (size_t)n*IC*H*H
                                 : inB + (size_t)(n - nSplit)*IC*H*H;
  __shared__ float sW[IC*9];
  for (int i = tid; i < IC*9; i += 256)
    sW[i] = W[(size_t)oc*IC*9 + i];   // W[oc][ic][kh][kw] contiguous
  __syncthreads();

  float ls = 0.f, lq = 0.f;
  for (int p = tid; p < H*H; p += 256) {
    const int y = p / H, x = p % H;
    float a = 0.f;
    for (int ic = 0; ic < IC; ++ic) {
      const float* ip = in + (size_t)ic*H*H;
      const float* wp = &sW[ic*9];
      #pragma unroll
      for (int kh = 0; kh < 3; ++kh) {
        const int yy = y + kh - 1;
        if (yy < 0 || yy >= H) continue;
        #pragma unroll
        for (int kw = 0; kw < 3; ++kw) {
          const int xx = x + kw - 1;
          if (xx < 0 || xx >= H) continue;
          a = fmaf(wp[kh*3 + kw], ip[yy*H + xx], a);
        }
      }
    }
    ls += a;
    lq = fmaf(a, a, lq);
  }

  __shared__ float rs[256], rq[256];
  rs[tid] = ls; rq[tid] = lq;
  __syncthreads();
  for (int s = 128; s > 0; s >>= 1) {
    if (tid < s) { rs[tid] += rs[tid + s]; rq[tid] += rq[tid + s]; }
    __syncthreads();
  }
  if (tid == 0) {
    const int g = (n < nSupport) ? 0 : 1;
    atomicAdd(&stats[(g*OC + oc)*2 + 0], (double)rs[0]);
    atomicAdd(&stats[(g*OC + oc)*2 + 1], (double)rq[0]);
  }
}

template<int IC, int OC, int H>
__global__ __launch_bounds__(256)
void conv_apply_v2(const float* __restrict__ inA, const float* __restrict__ inB,
                   int nSplit, const float* __restrict__ W,
                   const float* __restrict__ scale, const float* __restrict__ shift,
                   float* __restrict__ out, int nSupport)
{
  constexpr int Hp = H/2;
  const int n = blockIdx.z, oc = blockIdx.y, tid = threadIdx.x;
  const float* in = (n < nSplit) ? inA + (size_t)n*IC*H*H
                                 : inB + (size_t)(n - nSplit)*IC*H*H;
  __shared__ float sW[IC*9];
  for (int i = tid; i < IC*9; i += 256)
    sW[i] = W[(size_t)oc*IC*9 + i];
  __syncthreads();                 // all threads reach this before any exit

  const int p = blockIdx.x*256 + tid;
  if (p >= Hp*Hp) return;
  const int py = p / Hp, px = p % Hp;
  const int g = (n < nSupport) ? 0 : 1;
  const float s = scale[g*OC + oc];
  const float t = shift[g*OC + oc];

  float m = 0.f;                   // relu output >= 0
  #pragma unroll
  for (int dy = 0; dy < 2; ++dy) {
    #pragma unroll
    for (int dx = 0; dx < 2; ++dx) {
      const int y = 2*py + dy, x = 2*px + dx;
      float a = 0.f;
      for (int ic = 0; ic < IC; ++ic) {
        const float* ip = in + (size_t)ic*H*H;
        const float* wp = &sW[ic*9];
        #pragma unroll
        for (int kh = 0; kh < 3; ++kh) {
          const int yy = y + kh - 1;
          if (yy < 0 || yy >= H) continue;
          #pragma unroll
          for (int kw = 0; kw < 3; ++kw) {
            const int xx = x + kw - 1;
            if (xx < 0 || xx >= H) continue;
            a = fmaf(wp[kh*3 + kw], ip[yy*H + xx], a);
          }
        }
      }
      m = fmaxf(m, fmaxf(fmaf(a, s, t), 0.f));
    }
  }
  out[((size_t)(n*OC + oc)*Hp + py)*Hp + px] = m;
}

// ---------------------------------------------------------------------------
__global__ void bn_finalize(const double* __restrict__ stats,
                            const float* __restrict__ gamma, const float* __restrict__ beta,
                            float* __restrict__ scale, float* __restrict__ shift,
                            int OC, double cnt0, double cnt1)
{
  int i = threadIdx.x;
  if (i < 2*OC) {
    int oc = i % OC;
    double cnt = (i < OC) ? cnt0 : cnt1;
    double mean = stats[i*2 + 0] / cnt;
    double var  = stats[i*2 + 1] / cnt - mean*mean;
    double inv  = 1.0 / sqrt(var + 1e-5);
    double g = (double)gamma[oc];
    double b = (double)beta[oc];
    scale[i] = (float)(g * inv);
    shift[i] = (float)(b - mean * g * inv);
  }
}

// ---------------------------------------------------------------------------
__global__ void graph_means(const float* __restrict__ feat,
                            float* __restrict__ s_cat, float* __restrict__ p_cat)
{
  int g = blockIdx.x, d = threadIdx.x;
  if (g < 48) {
    float v = 0.f;
    for (int i = 0; i < 4; ++i) v += feat[(size_t)(4*g + i)*256 + d];
    s_cat[g*256 + d] = v * 0.25f;
  } else {
    int q = g - 48;
    float v = 0.f;
    for (int i = 0; i < 4; ++i) v += feat[(size_t)(192 + 4*q + i)*256 + d];
    p_cat[q*256 + d] = v * 0.25f;
  }
}

__global__ void edge_cos(const float* __restrict__ feat, const int* __restrict__ ei,
                         float* __restrict__ nsum, float* __restrict__ ncnt, int nEdges)
{
  int e = blockIdx.x, lane = threadIdx.x;
  int src = ei[e], dst = ei[nEdges + e];
  float dot = 0.f, nj = 0.f, ni = 0.f;
  for (int j = lane; j < 256; j += 64) {
    float a = feat[(size_t)src*256 + j];
    float b = feat[(size_t)dst*256 + j];
    dot += a*b; nj += a*a; ni += b*b;
  }
  for (int off = 32; off > 0; off >>= 1) {
    dot += __shfl_down(dot, off);
    nj  += __shfl_down(nj,  off);
    ni  += __shfl_down(ni,  off);
  }
  if (lane == 0) {
    float denom = fmaxf(sqrtf(nj)*sqrtf(ni), 1e-6f);
    atomicAdd(&nsum[dst], dot/denom);
    atomicAdd(&ncnt[dst], 1.f);
  }
}

__global__ void cos_loss_k(const float* __restrict__ nsum, const float* __restrict__ ncnt,
                           float* __restrict__ cosloss)
{
  int g = threadIdx.x;
  float v = 0.f;
  if (g < 48) {
    float gm = 0.f;
    for (int i = 0; i < 4; ++i) {
      int nd = 4*g + i;
      gm += nsum[nd] / fmaxf(ncnt[nd], 1.f);
    }
    gm *= 0.25f;
    v = (gm - 1.f)*(gm - 1.f);
  }
  for (int off = 32; off > 0; off >>= 1) v += __shfl_down(v, off);
  if (g == 0) cosloss[0] = v;
}

__global__ void pd_out(const float* __restrict__ s_cat, const float* __restrict__ p_cat,
                       const int* __restrict__ support_y, const int* __restrict__ query_y,
                       float* __restrict__ ce, float* __restrict__ correct)
{
  const int q = blockIdx.x;
  const int tid = threadIdx.x, lane = tid & 63, wid = tid >> 6;
  __shared__ float sP[48];
  __shared__ float sOut[24];
  float pv[4];
  #pragma unroll
  for (int j = 0; j < 4; ++j) pv[j] = p_cat[(size_t)q*256 + lane + 64*j];
  for (int s = wid*12; s < wid*12 + 12; ++s) {
    float d2 = 0.f;
    #pragma unroll
    for (int j = 0; j < 4; ++j) {
      float diff = pv[j] - s_cat[(size_t)s*256 + lane + 64*j];
      d2 += diff*diff;
    }
    for (int off = 32; off > 0; off >>= 1) d2 += __shfl_down(d2, off);
    if (lane == 0) sP[s] = expf(-d2);
  }
  __syncthreads();
  if (tid < 24) {
    int c = tid; float sum = 0.f; int cnt = 0;
    for (int s = 0; s < 48; ++s)
      if (support_y[s] == c) { sum += sP[s]; ++cnt; }
    sOut[c] = sum / fmaxf((float)cnt, 1.f);
  }
  __syncthreads();
  if (tid == 0) {
    float m = sOut[0]; int am = 0;
    for (int c = 1; c < 24; ++c) if (sOut[c] > m) { m = sOut[c]; am = c; }
    float lse = 0.f;
    for (int c = 0; c < 24; ++c) lse += expf(sOut[c] - m);
    lse = m + logf(lse);
    int y = query_y[q];
    ce[q] = lse - sOut[y];
    correct[q] = (am == y) ? 1.f : 0.f;
  }
}

__global__ void final_k(const float* __restrict__ ce, const float* __restrict__ correct,
                        const float* __restrict__ cosloss, float* __restrict__ out)
{
  if (threadIdx.x == 0) {
    float s = 0.f, a = 0.f;
    for (int qq = 0; qq < 24; ++qq) { s += ce[qq]; a += correct[qq]; }
    float atten = ce[5];
    float rest  = (s - atten) / 23.f;
    float cl = cosloss[0];
    out[0] = atten + rest + cl;   // loss
    out[1] = a;                   // acc
    out[2] = cl;                  // cos_loss
    out[3] = atten;               // atten_loss
    out[4] = rest;                // rest_loss
  }
}

// ---------------------------------------------------------------------------
extern "C" void kernel_launch(void* const* d_in, const int* in_sizes, int n_in,
                              void* d_out, int out_size, void* d_ws, size_t ws_size,
                              hipStream_t stream)
{
  const float* support_x = (const float*)d_in[0];
  const float* query_x   = (const float*)d_in[1];
  const int*   s_ei      = (const int*)d_in[2];
  const int*   s_y       = (const int*)d_in[6];
  const int*   q_y       = (const int*)d_in[7];
  const float* w1 = (const float*)d_in[8];
  const float* g1 = (const float*)d_in[9];
  const float* b1 = (const float*)d_in[10];
  const float* w2 = (const float*)d_in[11];
  const float* g2 = (const float*)d_in[12];
  const float* b2 = (const float*)d_in[13];
  const float* wr = (const float*)d_in[14];
  const float* gr = (const float*)d_in[15];
  const float* br = (const float*)d_in[16];
  (void)in_sizes; (void)n_in; (void)out_size;

  char* ws = (char*)d_ws;
  size_t off = 0;
  auto alloc = [&](size_t bytes) -> char* {
    char* p = ws + off;
    off = (off + bytes + 255) & ~(size_t)255;
    return p;
  };
  float*  actA  = (float*)alloc((size_t)288*32*64*64*4);   // 151 MB ping
  float*  actB  = (float*)alloc((size_t)288*64*32*32*4);   // 75.5 MB pong
  double* stats = (double*)alloc(2*64*2*8);
  float*  scl   = (float*)alloc(2*64*4);
  float*  shf   = (float*)alloc(2*64*4);
  float*  s_cat = (float*)alloc(48*256*4);
  float*  p_cat = (float*)alloc(24*256*4);
  float*  nsum  = (float*)alloc(192*4);
  float*  ncnt  = (float*)alloc(192*4);
  float*  cosl  = (float*)alloc(256);
  float*  ce    = (float*)alloc(24*4);
  float*  corr  = (float*)alloc(24*4);
  if (off > ws_size) return;

  const int NS = 192;
  const int BIG = 1 << 30;
  const size_t statsB = 2*64*2*8;

  // ---- L1: 3->32 @128, pool->64, out actA
  hipMemsetAsync(stats, 0, statsB, stream);
  conv_stats_v2<3,32,128><<<dim3(1,32,288),256,0,stream>>>(
      support_x, query_x, 192, w1, stats, NS);
  bn_finalize<<<1,128,0,stream>>>(stats, g1, b1, scl, shf, 32,
      192.0*128*128, 96.0*128*128);
  conv_apply_v2<3,32,128><<<dim3(16,32,288),256,0,stream>>>(
      support_x, query_x, 192, w1, scl, shf, actA, NS);

  // ---- L2: 32->64 @64, pool->32, out actB
  hipMemsetAsync(stats, 0, statsB, stream);
  conv_stats_v2<32,64,64><<<dim3(1,64,288),256,0,stream>>>(
      actA, actA, BIG, w2, stats, NS);
  bn_finalize<<<1,128,0,stream>>>(stats, g2, b2, scl, shf, 64,
      192.0*64*64, 96.0*64*64);
  conv_apply_v2<32,64,64><<<dim3(4,64,288),256,0,stream>>>(
      actA, actA, BIG, w2, scl, shf, actB, NS);

  // ---- L3: 64->64 @32, pool->16, out actA (w_rest[0])
  hipMemsetAsync(stats, 0, statsB, stream);
  conv_stats_v2<64,64,32><<<dim3(1,64,288),256,0,stream>>>(
      actB, actB, BIG, wr + 0*36864, stats, NS);
  bn_finalize<<<1,128,0,stream>>>(stats, gr + 0*64, br + 0*64, scl, shf, 64,
      192.0*32*32, 96.0*32*32);
  conv_apply_v2<64,64,32><<<dim3(1,64,288),256,0,stream>>>(
      actB, actB, BIG, wr + 0*36864, scl, shf, actA, NS);

  // ---- L4: 64->64 @16, pool->8, out actB (w_rest[1])
  hipMemsetAsync(stats, 0, statsB, stream);
  conv_stats_v2<64,64,16><<<dim3(1,64,288),256,0,stream>>>(
      actA, actA, BIG, wr + 1*36864, stats, NS);
  bn_finalize<<<1,128,0,stream>>>(stats, gr + 1*64, br + 1*64, scl, shf, 64,
      192.0*16*16, 96.0*16*16);
  conv_apply_v2<64,64,16><<<dim3(1,64,288),256,0,stream>>>(
      actA, actA, BIG, wr + 1*36864, scl, shf, actB, NS);

  // ---- L5: 64->64 @8, pool->4, out actA (w_rest[2])
  hipMemsetAsync(stats, 0, statsB, stream);
  conv_stats_v2<64,64,8><<<dim3(1,64,288),256,0,stream>>>(
      actB, actB, BIG, wr + 2*36864, stats, NS);
  bn_finalize<<<1,128,0,stream>>>(stats, gr + 2*64, br + 2*64, scl, shf, 64,
      192.0*8*8, 96.0*8*8);
  conv_apply_v2<64,64,8><<<dim3(1,64,288),256,0,stream>>>(
      actB, actB, BIG, wr + 2*36864, scl, shf, actA, NS);

  // ---- L6: 64->64 @4, pool->2, out actB = feat [288,256] (w_rest[3])
  hipMemsetAsync(stats, 0, statsB, stream);
  conv_stats_v2<64,64,4><<<dim3(1,64,288),256,0,stream>>>(
      actA, actA, BIG, wr + 3*36864, stats, NS);
  bn_finalize<<<1,128,0,stream>>>(stats, gr + 3*64, br + 3*64, scl, shf, 64,
      192.0*4*4, 96.0*4*4);
  conv_apply_v2<64,64,4><<<dim3(1,64,288),256,0,stream>>>(
      actA, actA, BIG, wr + 3*36864, scl, shf, actB, NS);

  // ---- head
  float* feat = actB;
  graph_means<<<72,256,0,stream>>>(feat, s_cat, p_cat);
  hipMemsetAsync(nsum, 0, 192*4, stream);
  hipMemsetAsync(ncnt, 0, 192*4, stream);
  edge_cos<<<768,64,0,stream>>>(feat, s_ei, nsum, ncnt, 768);
  cos_loss_k<<<1,64,0,stream>>>(nsum, ncnt, cosl);
  pd_out<<<24,256,0,stream>>>(s_cat, p_cat, s_y, q_y, ce, corr);
  final_k<<<1,64,0,stream>>>(ce, corr, cosl, (float*)d_out);
}

// Round 5
// 16317.723 us; speedup vs baseline: 2.0669x; 2.0669x over previous
//
#include <hip/hip_runtime.h>
#include <hip/hip_bf16.h>
#include <cstdint>
#include <cstddef>

// Inputs are all float32 (reference setup_inputs uses jnp.float32 throughout).
// R4 post-mortem: naive per-pixel apply kernels were latency-bound (VALUBusy
// 16-30%, HBM <1%) -- 4 dependent accumulators can't hide cache latency.
// R5: tiled apply (LDS input tile + 16-oc register blocking, 64 accumulators).

// ---------------------------------------------------------------------------
// Tiled conv 3x3 SAME + BN(scale,shift) + ReLU + 2x2 maxpool, one pass.
// Block: (TS/2)^2 threads; each thread owns one 2x2 conv quad (= one pool
// window) x OCG output channels. grid = (tiles^2, OC/OCG, N).
// ---------------------------------------------------------------------------
template<int IC, int OC, int H, int TS, int OCG>
__global__ __launch_bounds__(TS*TS/4)
void conv_apply_tiled(const float* __restrict__ inA, const float* __restrict__ inB,
                      int nSplit, const float* __restrict__ W,
                      const float* __restrict__ scale, const float* __restrict__ shift,
                      float* __restrict__ out, int nSupport)
{
  constexpr int TH = TS/2;
  constexpr int NT = TH*TH;
  constexpr int TILES = H/TS;
  const int tid = threadIdx.x;
  const int n   = blockIdx.z;
  const int ocg = blockIdx.y;
  const int ty0 = (blockIdx.x / TILES) * TS;
  const int tx0 = (blockIdx.x % TILES) * TS;

  const float* in = (n < nSplit) ? inA + (size_t)n*IC*H*H
                                 : inB + (size_t)(n - nSplit)*IC*H*H;

  __shared__ float sIn[(TS+2)*(TS+2)];
  __shared__ float sW[9*OCG];                 // [k][oc]

  float acc[4][OCG];
  #pragma unroll
  for (int i = 0; i < 4; ++i)
    #pragma unroll
    for (int o = 0; o < OCG; ++o) acc[i][o] = 0.f;

  const int tx = tid % TH, ty = tid / TH;
  const int iy = 2*ty, ix = 2*tx;

  for (int ic = 0; ic < IC; ++ic) {
    const float* ip = in + (size_t)ic*H*H;
    for (int i = tid; i < (TS+2)*(TS+2); i += NT) {
      int r = i/(TS+2), c = i%(TS+2);
      int gy = ty0 + r - 1, gx = tx0 + c - 1;
      float v = 0.f;
      if (gy >= 0 && gy < H && gx >= 0 && gx < H) v = ip[gy*H + gx];
      sIn[i] = v;
    }
    for (int i = tid; i < 9*OCG; i += NT) {
      int k = i / OCG, oc = i % OCG;
      sW[i] = W[((size_t)(ocg*OCG + oc)*IC + ic)*9 + k];
    }
    __syncthreads();
    #pragma unroll
    for (int kh = 0; kh < 3; ++kh) {
      #pragma unroll
      for (int kw = 0; kw < 3; ++kw) {
        float x00 = sIn[(iy+kh  )*(TS+2) + ix+kw  ];
        float x01 = sIn[(iy+kh  )*(TS+2) + ix+kw+1];
        float x10 = sIn[(iy+kh+1)*(TS+2) + ix+kw  ];
        float x11 = sIn[(iy+kh+1)*(TS+2) + ix+kw+1];
        const float* wk = &sW[(kh*3+kw)*OCG];
        #pragma unroll
        for (int oc = 0; oc < OCG; ++oc) {
          float wv = wk[oc];
          acc[0][oc] = fmaf(x00, wv, acc[0][oc]);
          acc[1][oc] = fmaf(x01, wv, acc[1][oc]);
          acc[2][oc] = fmaf(x10, wv, acc[2][oc]);
          acc[3][oc] = fmaf(x11, wv, acc[3][oc]);
        }
      }
    }
    __syncthreads();
  }

  const int g = (n < nSupport) ? 0 : 1;
  #pragma unroll
  for (int oc = 0; oc < OCG; ++oc) {
    const int ocGl = ocg*OCG + oc;
    const float s = scale[g*OC + ocGl];
    const float t = shift[g*OC + ocGl];
    float v0 = fmaxf(fmaf(acc[0][oc], s, t), 0.f);
    float v1 = fmaxf(fmaf(acc[1][oc], s, t), 0.f);
    float v2 = fmaxf(fmaf(acc[2][oc], s, t), 0.f);
    float v3 = fmaxf(fmaf(acc[3][oc], s, t), 0.f);
    float m = fmaxf(fmaxf(v0, v1), fmaxf(v2, v3));
    int py = ty0/2 + ty, px = tx0/2 + tx;
    out[(((size_t)n*OC + ocGl)*(H/2) + py)*(H/2) + px] = m;
  }
}

// ---------------------------------------------------------------------------
// Stats pass (unchanged from R4 -- measured cheap, latency hidden by 16
// independent pixel accumulators; 288 atomics/address = no contention).
// ---------------------------------------------------------------------------
template<int IC, int OC, int H>
__global__ __launch_bounds__(256)
void conv_stats_v2(const float* __restrict__ inA, const float* __restrict__ inB,
                   int nSplit, const float* __restrict__ W,
                   double* __restrict__ stats, int nSupport)
{
  const int n = blockIdx.z, oc = blockIdx.y, tid = threadIdx.x;
  const float* in = (n < nSplit) ? inA + (size_t)n*IC*H*H
                                 : inB + (size_t)(n - nSplit)*IC*H*H;
  __shared__ float sW[IC*9];
  for (int i = tid; i < IC*9; i += 256)
    sW[i] = W[(size_t)oc*IC*9 + i];
  __syncthreads();

  float ls = 0.f, lq = 0.f;
  for (int p = tid; p < H*H; p += 256) {
    const int y = p / H, x = p % H;
    float a = 0.f;
    for (int ic = 0; ic < IC; ++ic) {
      const float* ip = in + (size_t)ic*H*H;
      const float* wp = &sW[ic*9];
      #pragma unroll
      for (int kh = 0; kh < 3; ++kh) {
        const int yy = y + kh - 1;
        if (yy < 0 || yy >= H) continue;
        #pragma unroll
        for (int kw = 0; kw < 3; ++kw) {
          const int xx = x + kw - 1;
          if (xx < 0 || xx >= H) continue;
          a = fmaf(wp[kh*3 + kw], ip[yy*H + xx], a);
        }
      }
    }
    ls += a;
    lq = fmaf(a, a, lq);
  }

  __shared__ float rs[256], rq[256];
  rs[tid] = ls; rq[tid] = lq;
  __syncthreads();
  for (int s = 128; s > 0; s >>= 1) {
    if (tid < s) { rs[tid] += rs[tid + s]; rq[tid] += rq[tid + s]; }
    __syncthreads();
  }
  if (tid == 0) {
    const int g = (n < nSupport) ? 0 : 1;
    atomicAdd(&stats[(g*OC + oc)*2 + 0], (double)rs[0]);
    atomicAdd(&stats[(g*OC + oc)*2 + 1], (double)rq[0]);
  }
}

// Naive apply for the tiny layers (L5 H=8, L6 H=4) -- negligible cost.
template<int IC, int OC, int H>
__global__ __launch_bounds__(256)
void conv_apply_v2(const float* __restrict__ inA, const float* __restrict__ inB,
                   int nSplit, const float* __restrict__ W,
                   const float* __restrict__ scale, const float* __restrict__ shift,
                   float* __restrict__ out, int nSupport)
{
  constexpr int Hp = H/2;
  const int n = blockIdx.z, oc = blockIdx.y, tid = threadIdx.x;
  const float* in = (n < nSplit) ? inA + (size_t)n*IC*H*H
                                 : inB + (size_t)(n - nSplit)*IC*H*H;
  __shared__ float sW[IC*9];
  for (int i = tid; i < IC*9; i += 256)
    sW[i] = W[(size_t)oc*IC*9 + i];
  __syncthreads();

  const int p = blockIdx.x*256 + tid;
  if (p >= Hp*Hp) return;
  const int py = p / Hp, px = p % Hp;
  const int g = (n < nSupport) ? 0 : 1;
  const float s = scale[g*OC + oc];
  const float t = shift[g*OC + oc];

  float m = 0.f;
  #pragma unroll
  for (int dy = 0; dy < 2; ++dy) {
    #pragma unroll
    for (int dx = 0; dx < 2; ++dx) {
      const int y = 2*py + dy, x = 2*px + dx;
      float a = 0.f;
      for (int ic = 0; ic < IC; ++ic) {
        const float* ip = in + (size_t)ic*H*H;
        const float* wp = &sW[ic*9];
        #pragma unroll
        for (int kh = 0; kh < 3; ++kh) {
          const int yy = y + kh - 1;
          if (yy < 0 || yy >= H) continue;
          #pragma unroll
          for (int kw = 0; kw < 3; ++kw) {
            const int xx = x + kw - 1;
            if (xx < 0 || xx >= H) continue;
            a = fmaf(wp[kh*3 + kw], ip[yy*H + xx], a);
          }
        }
      }
      m = fmaxf(m, fmaxf(fmaf(a, s, t), 0.f));
    }
  }
  out[((size_t)(n*OC + oc)*Hp + py)*Hp + px] = m;
}

// ---------------------------------------------------------------------------
__global__ void bn_finalize(const double* __restrict__ stats,
                            const float* __restrict__ gamma, const float* __restrict__ beta,
                            float* __restrict__ scale, float* __restrict__ shift,
                            int OC, double cnt0, double cnt1)
{
  int i = threadIdx.x;
  if (i < 2*OC) {
    int oc = i % OC;
    double cnt = (i < OC) ? cnt0 : cnt1;
    double mean = stats[i*2 + 0] / cnt;
    double var  = stats[i*2 + 1] / cnt - mean*mean;
    double inv  = 1.0 / sqrt(var + 1e-5);
    double g = (double)gamma[oc];
    double b = (double)beta[oc];
    scale[i] = (float)(g * inv);
    shift[i] = (float)(b - mean * g * inv);
  }
}

// ---------------------------------------------------------------------------
__global__ void graph_means(const float* __restrict__ feat,
                            float* __restrict__ s_cat, float* __restrict__ p_cat)
{
  int g = blockIdx.x, d = threadIdx.x;
  if (g < 48) {
    float v = 0.f;
    for (int i = 0; i < 4; ++i) v += feat[(size_t)(4*g + i)*256 + d];
    s_cat[g*256 + d] = v * 0.25f;
  } else {
    int q = g - 48;
    float v = 0.f;
    for (int i = 0; i < 4; ++i) v += feat[(size_t)(192 + 4*q + i)*256 + d];
    p_cat[q*256 + d] = v * 0.25f;
  }
}

__global__ void edge_cos(const float* __restrict__ feat, const int* __restrict__ ei,
                         float* __restrict__ nsum, float* __restrict__ ncnt, int nEdges)
{
  int e = blockIdx.x, lane = threadIdx.x;
  int src = ei[e], dst = ei[nEdges + e];
  float dot = 0.f, nj = 0.f, ni = 0.f;
  for (int j = lane; j < 256; j += 64) {
    float a = feat[(size_t)src*256 + j];
    float b = feat[(size_t)dst*256 + j];
    dot += a*b; nj += a*a; ni += b*b;
  }
  for (int off = 32; off > 0; off >>= 1) {
    dot += __shfl_down(dot, off);
    nj  += __shfl_down(nj,  off);
    ni  += __shfl_down(ni,  off);
  }
  if (lane == 0) {
    float denom = fmaxf(sqrtf(nj)*sqrtf(ni), 1e-6f);
    atomicAdd(&nsum[dst], dot/denom);
    atomicAdd(&ncnt[dst], 1.f);
  }
}

__global__ void cos_loss_k(const float* __restrict__ nsum, const float* __restrict__ ncnt,
                           float* __restrict__ cosloss)
{
  int g = threadIdx.x;
  float v = 0.f;
  if (g < 48) {
    float gm = 0.f;
    for (int i = 0; i < 4; ++i) {
      int nd = 4*g + i;
      gm += nsum[nd] / fmaxf(ncnt[nd], 1.f);
    }
    gm *= 0.25f;
    v = (gm - 1.f)*(gm - 1.f);
  }
  for (int off = 32; off > 0; off >>= 1) v += __shfl_down(v, off);
  if (g == 0) cosloss[0] = v;
}

__global__ void pd_out(const float* __restrict__ s_cat, const float* __restrict__ p_cat,
                       const int* __restrict__ support_y, const int* __restrict__ query_y,
                       float* __restrict__ ce, float* __restrict__ correct)
{
  const int q = blockIdx.x;
  const int tid = threadIdx.x, lane = tid & 63, wid = tid >> 6;
  __shared__ float sP[48];
  __shared__ float sOut[24];
  float pv[4];
  #pragma unroll
  for (int j = 0; j < 4; ++j) pv[j] = p_cat[(size_t)q*256 + lane + 64*j];
  for (int s = wid*12; s < wid*12 + 12; ++s) {
    float d2 = 0.f;
    #pragma unroll
    for (int j = 0; j < 4; ++j) {
      float diff = pv[j] - s_cat[(size_t)s*256 + lane + 64*j];
      d2 += diff*diff;
    }
    for (int off = 32; off > 0; off >>= 1) d2 += __shfl_down(d2, off);
    if (lane == 0) sP[s] = expf(-d2);
  }
  __syncthreads();
  if (tid < 24) {
    int c = tid; float sum = 0.f; int cnt = 0;
    for (int s = 0; s < 48; ++s)
      if (support_y[s] == c) { sum += sP[s]; ++cnt; }
    sOut[c] = sum / fmaxf((float)cnt, 1.f);
  }
  __syncthreads();
  if (tid == 0) {
    float m = sOut[0]; int am = 0;
    for (int c = 1; c < 24; ++c) if (sOut[c] > m) { m = sOut[c]; am = c; }
    float lse = 0.f;
    for (int c = 0; c < 24; ++c) lse += expf(sOut[c] - m);
    lse = m + logf(lse);
    int y = query_y[q];
    ce[q] = lse - sOut[y];
    correct[q] = (am == y) ? 1.f : 0.f;
  }
}

__global__ void final_k(const float* __restrict__ ce, const float* __restrict__ correct,
                        const float* __restrict__ cosloss, float* __restrict__ out)
{
  if (threadIdx.x == 0) {
    float s = 0.f, a = 0.f;
    for (int qq = 0; qq < 24; ++qq) { s += ce[qq]; a += correct[qq]; }
    float atten = ce[5];
    float rest  = (s - atten) / 23.f;
    float cl = cosloss[0];
    out[0] = atten + rest + cl;
    out[1] = a;
    out[2] = cl;
    out[3] = atten;
    out[4] = rest;
  }
}

// ---------------------------------------------------------------------------
extern "C" void kernel_launch(void* const* d_in, const int* in_sizes, int n_in,
                              void* d_out, int out_size, void* d_ws, size_t ws_size,
                              hipStream_t stream)
{
  const float* support_x = (const float*)d_in[0];
  const float* query_x   = (const float*)d_in[1];
  const int*   s_ei      = (const int*)d_in[2];
  const int*   s_y       = (const int*)d_in[6];
  const int*   q_y       = (const int*)d_in[7];
  const float* w1 = (const float*)d_in[8];
  const float* g1 = (const float*)d_in[9];
  const float* b1 = (const float*)d_in[10];
  const float* w2 = (const float*)d_in[11];
  const float* g2 = (const float*)d_in[12];
  const float* b2 = (const float*)d_in[13];
  const float* wr = (const float*)d_in[14];
  const float* gr = (const float*)d_in[15];
  const float* br = (const float*)d_in[16];
  (void)in_sizes; (void)n_in; (void)out_size;

  char* ws = (char*)d_ws;
  size_t off = 0;
  auto alloc = [&](size_t bytes) -> char* {
    char* p = ws + off;
    off = (off + bytes + 255) & ~(size_t)255;
    return p;
  };
  float*  actA  = (float*)alloc((size_t)288*32*64*64*4);   // 151 MB ping
  float*  actB  = (float*)alloc((size_t)288*64*32*32*4);   // 75.5 MB pong
  double* stats = (double*)alloc(2*64*2*8);
  float*  scl   = (float*)alloc(2*64*4);
  float*  shf   = (float*)alloc(2*64*4);
  float*  s_cat = (float*)alloc(48*256*4);
  float*  p_cat = (float*)alloc(24*256*4);
  float*  nsum  = (float*)alloc(192*4);
  float*  ncnt  = (float*)alloc(192*4);
  float*  cosl  = (float*)alloc(256);
  float*  ce    = (float*)alloc(24*4);
  float*  corr  = (float*)alloc(24*4);
  if (off > ws_size) return;

  const int NS = 192;
  const int BIG = 1 << 30;
  const size_t statsB = 2*64*2*8;

  // ---- L1: 3->32 @128, pool->64, out actA
  hipMemsetAsync(stats, 0, statsB, stream);
  conv_stats_v2<3,32,128><<<dim3(1,32,288),256,0,stream>>>(
      support_x, query_x, 192, w1, stats, NS);
  bn_finalize<<<1,128,0,stream>>>(stats, g1, b1, scl, shf, 32,
      192.0*128*128, 96.0*128*128);
  conv_apply_tiled<3,32,128,32,16><<<dim3(16,2,288),256,0,stream>>>(
      support_x, query_x, 192, w1, scl, shf, actA, NS);

  // ---- L2: 32->64 @64, pool->32, out actB
  hipMemsetAsync(stats, 0, statsB, stream);
  conv_stats_v2<32,64,64><<<dim3(1,64,288),256,0,stream>>>(
      actA, actA, BIG, w2, stats, NS);
  bn_finalize<<<1,128,0,stream>>>(stats, g2, b2, scl, shf, 64,
      192.0*64*64, 96.0*64*64);
  conv_apply_tiled<32,64,64,32,16><<<dim3(4,4,288),256,0,stream>>>(
      actA, actA, BIG, w2, scl, shf, actB, NS);

  // ---- L3: 64->64 @32, pool->16, out actA (w_rest[0])
  hipMemsetAsync(stats, 0, statsB, stream);
  conv_stats_v2<64,64,32><<<dim3(1,64,288),256,0,stream>>>(
      actB, actB, BIG, wr + 0*36864, stats, NS);
  bn_finalize<<<1,128,0,stream>>>(stats, gr + 0*64, br + 0*64, scl, shf, 64,
      192.0*32*32, 96.0*32*32);
  conv_apply_tiled<64,64,32,32,16><<<dim3(1,4,288),256,0,stream>>>(
      actB, actB, BIG, wr + 0*36864, scl, shf, actA, NS);

  // ---- L4: 64->64 @16, pool->8, out actB (w_rest[1])
  hipMemsetAsync(stats, 0, statsB, stream);
  conv_stats_v2<64,64,16><<<dim3(1,64,288),256,0,stream>>>(
      actA, actA, BIG, wr + 1*36864, stats, NS);
  bn_finalize<<<1,128,0,stream>>>(stats, gr + 1*64, br + 1*64, scl, shf, 64,
      192.0*16*16, 96.0*16*16);
  conv_apply_tiled<64,64,16,16,16><<<dim3(1,4,288),64,0,stream>>>(
      actA, actA, BIG, wr + 1*36864, scl, shf, actB, NS);

  // ---- L5: 64->64 @8, pool->4, out actA (w_rest[2])
  hipMemsetAsync(stats, 0, statsB, stream);
  conv_stats_v2<64,64,8><<<dim3(1,64,288),256,0,stream>>>(
      actB, actB, BIG, wr + 2*36864, stats, NS);
  bn_finalize<<<1,128,0,stream>>>(stats, gr + 2*64, br + 2*64, scl, shf, 64,
      192.0*8*8, 96.0*8*8);
  conv_apply_v2<64,64,8><<<dim3(1,64,288),256,0,stream>>>(
      actB, actB, BIG, wr + 2*36864, scl, shf, actA, NS);

  // ---- L6: 64->64 @4, pool->2, out actB = feat [288,256] (w_rest[3])
  hipMemsetAsync(stats, 0, statsB, stream);
  conv_stats_v2<64,64,4><<<dim3(1,64,288),256,0,stream>>>(
      actA, actA, BIG, wr + 3*36864, stats, NS);
  bn_finalize<<<1,128,0,stream>>>(stats, gr + 3*64, br + 3*64, scl, shf, 64,
      192.0*4*4, 96.0*4*4);
  conv_apply_v2<64,64,4><<<dim3(1,64,288),256,0,stream>>>(
      actA, actA, BIG, wr + 3*36864, scl, shf, actB, NS);

  // ---- head
  float* feat = actB;
  graph_means<<<72,256,0,stream>>>(feat, s_cat, p_cat);
  hipMemsetAsync(nsum, 0, 192*4, stream);
  hipMemsetAsync(ncnt, 0, 192*4, stream);
  edge_cos<<<768,64,0,stream>>>(feat, s_ei, nsum, ncnt, 768);
  cos_loss_k<<<1,64,0,stream>>>(nsum, ncnt, cosl);
  pd_out<<<24,256,0,stream>>>(s_cat, p_cat, s_y, q_y, ce, corr);
  final_k<<<1,64,0,stream>>>(ce, corr, cosl, (float*)d_out);
}

// Round 6
// 6165.160 us; speedup vs baseline: 5.4705x; 2.6468x over previous
//
#include <hip/hip_runtime.h>
#include <hip/hip_bf16.h>
#include <cstdint>
#include <cstddef>

// Inputs are all float32. R5 post-mortem: stats passes were latency-bound
// (VALUBusy ~25%, 1 outstanding load chain per thread). R6: tiled stats --
// same LDS-staged conv main loop as conv_apply_tiled (validated), epilogue
// reduces per-oc sum/sumsq instead of writing pixels.

// ---------------------------------------------------------------------------
// Tiled conv 3x3 SAME + BN(scale,shift) + ReLU + 2x2 maxpool, one pass.
// Block: (TS/2)^2 threads; each thread owns one 2x2 conv quad x OCG ocs.
// grid = (tiles^2, OC/OCG, N).
// ---------------------------------------------------------------------------
template<int IC, int OC, int H, int TS, int OCG>
__global__ __launch_bounds__(TS*TS/4)
void conv_apply_tiled(const float* __restrict__ inA, const float* __restrict__ inB,
                      int nSplit, const float* __restrict__ W,
                      const float* __restrict__ scale, const float* __restrict__ shift,
                      float* __restrict__ out, int nSupport)
{
  constexpr int TH = TS/2;
  constexpr int NT = TH*TH;
  constexpr int TILES = H/TS;
  const int tid = threadIdx.x;
  const int n   = blockIdx.z;
  const int ocg = blockIdx.y;
  const int ty0 = (blockIdx.x / TILES) * TS;
  const int tx0 = (blockIdx.x % TILES) * TS;

  const float* in = (n < nSplit) ? inA + (size_t)n*IC*H*H
                                 : inB + (size_t)(n - nSplit)*IC*H*H;

  __shared__ float sIn[(TS+2)*(TS+2)];
  __shared__ float sW[9*OCG];                 // [k][oc]

  float acc[4][OCG];
  #pragma unroll
  for (int i = 0; i < 4; ++i)
    #pragma unroll
    for (int o = 0; o < OCG; ++o) acc[i][o] = 0.f;

  const int tx = tid % TH, ty = tid / TH;
  const int iy = 2*ty, ix = 2*tx;

  for (int ic = 0; ic < IC; ++ic) {
    const float* ip = in + (size_t)ic*H*H;
    for (int i = tid; i < (TS+2)*(TS+2); i += NT) {
      int r = i/(TS+2), c = i%(TS+2);
      int gy = ty0 + r - 1, gx = tx0 + c - 1;
      float v = 0.f;
      if (gy >= 0 && gy < H && gx >= 0 && gx < H) v = ip[gy*H + gx];
      sIn[i] = v;
    }
    for (int i = tid; i < 9*OCG; i += NT) {
      int k = i / OCG, oc = i % OCG;
      sW[i] = W[((size_t)(ocg*OCG + oc)*IC + ic)*9 + k];
    }
    __syncthreads();
    #pragma unroll
    for (int kh = 0; kh < 3; ++kh) {
      #pragma unroll
      for (int kw = 0; kw < 3; ++kw) {
        float x00 = sIn[(iy+kh  )*(TS+2) + ix+kw  ];
        float x01 = sIn[(iy+kh  )*(TS+2) + ix+kw+1];
        float x10 = sIn[(iy+kh+1)*(TS+2) + ix+kw  ];
        float x11 = sIn[(iy+kh+1)*(TS+2) + ix+kw+1];
        const float* wk = &sW[(kh*3+kw)*OCG];
        #pragma unroll
        for (int oc = 0; oc < OCG; ++oc) {
          float wv = wk[oc];
          acc[0][oc] = fmaf(x00, wv, acc[0][oc]);
          acc[1][oc] = fmaf(x01, wv, acc[1][oc]);
          acc[2][oc] = fmaf(x10, wv, acc[2][oc]);
          acc[3][oc] = fmaf(x11, wv, acc[3][oc]);
        }
      }
    }
    __syncthreads();
  }

  const int g = (n < nSupport) ? 0 : 1;
  #pragma unroll
  for (int oc = 0; oc < OCG; ++oc) {
    const int ocGl = ocg*OCG + oc;
    const float s = scale[g*OC + ocGl];
    const float t = shift[g*OC + ocGl];
    float v0 = fmaxf(fmaf(acc[0][oc], s, t), 0.f);
    float v1 = fmaxf(fmaf(acc[1][oc], s, t), 0.f);
    float v2 = fmaxf(fmaf(acc[2][oc], s, t), 0.f);
    float v3 = fmaxf(fmaf(acc[3][oc], s, t), 0.f);
    float m = fmaxf(fmaxf(v0, v1), fmaxf(v2, v3));
    int py = ty0/2 + ty, px = tx0/2 + tx;
    out[(((size_t)n*OC + ocGl)*(H/2) + py)*(H/2) + px] = m;
  }
}

// ---------------------------------------------------------------------------
// Tiled stats: identical main loop; epilogue reduces per-oc sum/sumsq of the
// conv output across the block, then 2 f64 atomics per oc per block.
// ---------------------------------------------------------------------------
template<int IC, int OC, int H, int TS, int OCG>
__global__ __launch_bounds__(TS*TS/4)
void conv_stats_tiled(const float* __restrict__ inA, const float* __restrict__ inB,
                      int nSplit, const float* __restrict__ W,
                      double* __restrict__ stats, int nSupport)
{
  constexpr int TH = TS/2;
  constexpr int NT = TH*TH;
  constexpr int NW = NT/64;
  constexpr int TILES = H/TS;
  const int tid = threadIdx.x;
  const int n   = blockIdx.z;
  const int ocg = blockIdx.y;
  const int ty0 = (blockIdx.x / TILES) * TS;
  const int tx0 = (blockIdx.x % TILES) * TS;

  const float* in = (n < nSplit) ? inA + (size_t)n*IC*H*H
                                 : inB + (size_t)(n - nSplit)*IC*H*H;

  __shared__ float sIn[(TS+2)*(TS+2)];
  __shared__ float sW[9*OCG];
  __shared__ float sSum[NW][OCG], sSsq[NW][OCG];

  float acc[4][OCG];
  #pragma unroll
  for (int i = 0; i < 4; ++i)
    #pragma unroll
    for (int o = 0; o < OCG; ++o) acc[i][o] = 0.f;

  const int tx = tid % TH, ty = tid / TH;
  const int iy = 2*ty, ix = 2*tx;

  for (int ic = 0; ic < IC; ++ic) {
    const float* ip = in + (size_t)ic*H*H;
    for (int i = tid; i < (TS+2)*(TS+2); i += NT) {
      int r = i/(TS+2), c = i%(TS+2);
      int gy = ty0 + r - 1, gx = tx0 + c - 1;
      float v = 0.f;
      if (gy >= 0 && gy < H && gx >= 0 && gx < H) v = ip[gy*H + gx];
      sIn[i] = v;
    }
    for (int i = tid; i < 9*OCG; i += NT) {
      int k = i / OCG, oc = i % OCG;
      sW[i] = W[((size_t)(ocg*OCG + oc)*IC + ic)*9 + k];
    }
    __syncthreads();
    #pragma unroll
    for (int kh = 0; kh < 3; ++kh) {
      #pragma unroll
      for (int kw = 0; kw < 3; ++kw) {
        float x00 = sIn[(iy+kh  )*(TS+2) + ix+kw  ];
        float x01 = sIn[(iy+kh  )*(TS+2) + ix+kw+1];
        float x10 = sIn[(iy+kh+1)*(TS+2) + ix+kw  ];
        float x11 = sIn[(iy+kh+1)*(TS+2) + ix+kw+1];
        const float* wk = &sW[(kh*3+kw)*OCG];
        #pragma unroll
        for (int oc = 0; oc < OCG; ++oc) {
          float wv = wk[oc];
          acc[0][oc] = fmaf(x00, wv, acc[0][oc]);
          acc[1][oc] = fmaf(x01, wv, acc[1][oc]);
          acc[2][oc] = fmaf(x10, wv, acc[2][oc]);
          acc[3][oc] = fmaf(x11, wv, acc[3][oc]);
        }
      }
    }
    __syncthreads();
  }

  const int lane = tid & 63, wid = tid >> 6;
  #pragma unroll
  for (int oc = 0; oc < OCG; ++oc) {
    float ls = acc[0][oc] + acc[1][oc] + acc[2][oc] + acc[3][oc];
    float lq = acc[0][oc]*acc[0][oc] + acc[1][oc]*acc[1][oc]
             + acc[2][oc]*acc[2][oc] + acc[3][oc]*acc[3][oc];
    #pragma unroll
    for (int off = 32; off > 0; off >>= 1) {
      ls += __shfl_down(ls, off);
      lq += __shfl_down(lq, off);
    }
    if (lane == 0) { sSum[wid][oc] = ls; sSsq[wid][oc] = lq; }
  }
  __syncthreads();
  if (tid < OCG) {
    float S = 0.f, Q = 0.f;
    #pragma unroll
    for (int w = 0; w < NW; ++w) { S += sSum[w][tid]; Q += sSsq[w][tid]; }
    const int g = (n < nSupport) ? 0 : 1;
    const int ocGl = ocg*OCG + tid;
    atomicAdd(&stats[(g*OC + ocGl)*2 + 0], (double)S);
    atomicAdd(&stats[(g*OC + ocGl)*2 + 1], (double)Q);
  }
}

// ---------------------------------------------------------------------------
// Naive stats/apply for the tiny layers (L5 H=8, L6 H=4) -- measured cheap.
// ---------------------------------------------------------------------------
template<int IC, int OC, int H>
__global__ __launch_bounds__(256)
void conv_stats_v2(const float* __restrict__ inA, const float* __restrict__ inB,
                   int nSplit, const float* __restrict__ W,
                   double* __restrict__ stats, int nSupport)
{
  const int n = blockIdx.z, oc = blockIdx.y, tid = threadIdx.x;
  const float* in = (n < nSplit) ? inA + (size_t)n*IC*H*H
                                 : inB + (size_t)(n - nSplit)*IC*H*H;
  __shared__ float sW[IC*9];
  for (int i = tid; i < IC*9; i += 256)
    sW[i] = W[(size_t)oc*IC*9 + i];
  __syncthreads();

  float ls = 0.f, lq = 0.f;
  for (int p = tid; p < H*H; p += 256) {
    const int y = p / H, x = p % H;
    float a = 0.f;
    for (int ic = 0; ic < IC; ++ic) {
      const float* ip = in + (size_t)ic*H*H;
      const float* wp = &sW[ic*9];
      #pragma unroll
      for (int kh = 0; kh < 3; ++kh) {
        const int yy = y + kh - 1;
        if (yy < 0 || yy >= H) continue;
        #pragma unroll
        for (int kw = 0; kw < 3; ++kw) {
          const int xx = x + kw - 1;
          if (xx < 0 || xx >= H) continue;
          a = fmaf(wp[kh*3 + kw], ip[yy*H + xx], a);
        }
      }
    }
    ls += a;
    lq = fmaf(a, a, lq);
  }

  __shared__ float rs[256], rq[256];
  rs[tid] = ls; rq[tid] = lq;
  __syncthreads();
  for (int s = 128; s > 0; s >>= 1) {
    if (tid < s) { rs[tid] += rs[tid + s]; rq[tid] += rq[tid + s]; }
    __syncthreads();
  }
  if (tid == 0) {
    const int g = (n < nSupport) ? 0 : 1;
    atomicAdd(&stats[(g*OC + oc)*2 + 0], (double)rs[0]);
    atomicAdd(&stats[(g*OC + oc)*2 + 1], (double)rq[0]);
  }
}

template<int IC, int OC, int H>
__global__ __launch_bounds__(256)
void conv_apply_v2(const float* __restrict__ inA, const float* __restrict__ inB,
                   int nSplit, const float* __restrict__ W,
                   const float* __restrict__ scale, const float* __restrict__ shift,
                   float* __restrict__ out, int nSupport)
{
  constexpr int Hp = H/2;
  const int n = blockIdx.z, oc = blockIdx.y, tid = threadIdx.x;
  const float* in = (n < nSplit) ? inA + (size_t)n*IC*H*H
                                 : inB + (size_t)(n - nSplit)*IC*H*H;
  __shared__ float sW[IC*9];
  for (int i = tid; i < IC*9; i += 256)
    sW[i] = W[(size_t)oc*IC*9 + i];
  __syncthreads();

  const int p = blockIdx.x*256 + tid;
  if (p >= Hp*Hp) return;
  const int py = p / Hp, px = p % Hp;
  const int g = (n < nSupport) ? 0 : 1;
  const float s = scale[g*OC + oc];
  const float t = shift[g*OC + oc];

  float m = 0.f;
  #pragma unroll
  for (int dy = 0; dy < 2; ++dy) {
    #pragma unroll
    for (int dx = 0; dx < 2; ++dx) {
      const int y = 2*py + dy, x = 2*px + dx;
      float a = 0.f;
      for (int ic = 0; ic < IC; ++ic) {
        const float* ip = in + (size_t)ic*H*H;
        const float* wp = &sW[ic*9];
        #pragma unroll
        for (int kh = 0; kh < 3; ++kh) {
          const int yy = y + kh - 1;
          if (yy < 0 || yy >= H) continue;
          #pragma unroll
          for (int kw = 0; kw < 3; ++kw) {
            const int xx = x + kw - 1;
            if (xx < 0 || xx >= H) continue;
            a = fmaf(wp[kh*3 + kw], ip[yy*H + xx], a);
          }
        }
      }
      m = fmaxf(m, fmaxf(fmaf(a, s, t), 0.f));
    }
  }
  out[((size_t)(n*OC + oc)*Hp + py)*Hp + px] = m;
}

// ---------------------------------------------------------------------------
__global__ void bn_finalize(const double* __restrict__ stats,
                            const float* __restrict__ gamma, const float* __restrict__ beta,
                            float* __restrict__ scale, float* __restrict__ shift,
                            int OC, double cnt0, double cnt1)
{
  int i = threadIdx.x;
  if (i < 2*OC) {
    int oc = i % OC;
    double cnt = (i < OC) ? cnt0 : cnt1;
    double mean = stats[i*2 + 0] / cnt;
    double var  = stats[i*2 + 1] / cnt - mean*mean;
    double inv  = 1.0 / sqrt(var + 1e-5);
    double g = (double)gamma[oc];
    double b = (double)beta[oc];
    scale[i] = (float)(g * inv);
    shift[i] = (float)(b - mean * g * inv);
  }
}

// ---------------------------------------------------------------------------
__global__ void graph_means(const float* __restrict__ feat,
                            float* __restrict__ s_cat, float* __restrict__ p_cat)
{
  int g = blockIdx.x, d = threadIdx.x;
  if (g < 48) {
    float v = 0.f;
    for (int i = 0; i < 4; ++i) v += feat[(size_t)(4*g + i)*256 + d];
    s_cat[g*256 + d] = v * 0.25f;
  } else {
    int q = g - 48;
    float v = 0.f;
    for (int i = 0; i < 4; ++i) v += feat[(size_t)(192 + 4*q + i)*256 + d];
    p_cat[q*256 + d] = v * 0.25f;
  }
}

__global__ void edge_cos(const float* __restrict__ feat, const int* __restrict__ ei,
                         float* __restrict__ nsum, float* __restrict__ ncnt, int nEdges)
{
  int e = blockIdx.x, lane = threadIdx.x;
  int src = ei[e], dst = ei[nEdges + e];
  float dot = 0.f, nj = 0.f, ni = 0.f;
  for (int j = lane; j < 256; j += 64) {
    float a = feat[(size_t)src*256 + j];
    float b = feat[(size_t)dst*256 + j];
    dot += a*b; nj += a*a; ni += b*b;
  }
  for (int off = 32; off > 0; off >>= 1) {
    dot += __shfl_down(dot, off);
    nj  += __shfl_down(nj,  off);
    ni  += __shfl_down(ni,  off);
  }
  if (lane == 0) {
    float denom = fmaxf(sqrtf(nj)*sqrtf(ni), 1e-6f);
    atomicAdd(&nsum[dst], dot/denom);
    atomicAdd(&ncnt[dst], 1.f);
  }
}

__global__ void cos_loss_k(const float* __restrict__ nsum, const float* __restrict__ ncnt,
                           float* __restrict__ cosloss)
{
  int g = threadIdx.x;
  float v = 0.f;
  if (g < 48) {
    float gm = 0.f;
    for (int i = 0; i < 4; ++i) {
      int nd = 4*g + i;
      gm += nsum[nd] / fmaxf(ncnt[nd], 1.f);
    }
    gm *= 0.25f;
    v = (gm - 1.f)*(gm - 1.f);
  }
  for (int off = 32; off > 0; off >>= 1) v += __shfl_down(v, off);
  if (g == 0) cosloss[0] = v;
}

__global__ void pd_out(const float* __restrict__ s_cat, const float* __restrict__ p_cat,
                       const int* __restrict__ support_y, const int* __restrict__ query_y,
                       float* __restrict__ ce, float* __restrict__ correct)
{
  const int q = blockIdx.x;
  const int tid = threadIdx.x, lane = tid & 63, wid = tid >> 6;
  __shared__ float sP[48];
  __shared__ float sOut[24];
  float pv[4];
  #pragma unroll
  for (int j = 0; j < 4; ++j) pv[j] = p_cat[(size_t)q*256 + lane + 64*j];
  for (int s = wid*12; s < wid*12 + 12; ++s) {
    float d2 = 0.f;
    #pragma unroll
    for (int j = 0; j < 4; ++j) {
      float diff = pv[j] - s_cat[(size_t)s*256 + lane + 64*j];
      d2 += diff*diff;
    }
    for (int off = 32; off > 0; off >>= 1) d2 += __shfl_down(d2, off);
    if (lane == 0) sP[s] = expf(-d2);
  }
  __syncthreads();
  if (tid < 24) {
    int c = tid; float sum = 0.f; int cnt = 0;
    for (int s = 0; s < 48; ++s)
      if (support_y[s] == c) { sum += sP[s]; ++cnt; }
    sOut[c] = sum / fmaxf((float)cnt, 1.f);
  }
  __syncthreads();
  if (tid == 0) {
    float m = sOut[0]; int am = 0;
    for (int c = 1; c < 24; ++c) if (sOut[c] > m) { m = sOut[c]; am = c; }
    float lse = 0.f;
    for (int c = 0; c < 24; ++c) lse += expf(sOut[c] - m);
    lse = m + logf(lse);
    int y = query_y[q];
    ce[q] = lse - sOut[y];
    correct[q] = (am == y) ? 1.f : 0.f;
  }
}

__global__ void final_k(const float* __restrict__ ce, const float* __restrict__ correct,
                        const float* __restrict__ cosloss, float* __restrict__ out)
{
  if (threadIdx.x == 0) {
    float s = 0.f, a = 0.f;
    for (int qq = 0; qq < 24; ++qq) { s += ce[qq]; a += correct[qq]; }
    float atten = ce[5];
    float rest  = (s - atten) / 23.f;
    float cl = cosloss[0];
    out[0] = atten + rest + cl;
    out[1] = a;
    out[2] = cl;
    out[3] = atten;
    out[4] = rest;
  }
}

// ---------------------------------------------------------------------------
extern "C" void kernel_launch(void* const* d_in, const int* in_sizes, int n_in,
                              void* d_out, int out_size, void* d_ws, size_t ws_size,
                              hipStream_t stream)
{
  const float* support_x = (const float*)d_in[0];
  const float* query_x   = (const float*)d_in[1];
  const int*   s_ei      = (const int*)d_in[2];
  const int*   s_y       = (const int*)d_in[6];
  const int*   q_y       = (const int*)d_in[7];
  const float* w1 = (const float*)d_in[8];
  const float* g1 = (const float*)d_in[9];
  const float* b1 = (const float*)d_in[10];
  const float* w2 = (const float*)d_in[11];
  const float* g2 = (const float*)d_in[12];
  const float* b2 = (const float*)d_in[13];
  const float* wr = (const float*)d_in[14];
  const float* gr = (const float*)d_in[15];
  const float* br = (const float*)d_in[16];
  (void)in_sizes; (void)n_in; (void)out_size;

  char* ws = (char*)d_ws;
  size_t off = 0;
  auto alloc = [&](size_t bytes) -> char* {
    char* p = ws + off;
    off = (off + bytes + 255) & ~(size_t)255;
    return p;
  };
  float*  actA  = (float*)alloc((size_t)288*32*64*64*4);   // 151 MB ping
  float*  actB  = (float*)alloc((size_t)288*64*32*32*4);   // 75.5 MB pong
  double* stats = (double*)alloc(2*64*2*8);
  float*  scl   = (float*)alloc(2*64*4);
  float*  shf   = (float*)alloc(2*64*4);
  float*  s_cat = (float*)alloc(48*256*4);
  float*  p_cat = (float*)alloc(24*256*4);
  float*  nsum  = (float*)alloc(192*4);
  float*  ncnt  = (float*)alloc(192*4);
  float*  cosl  = (float*)alloc(256);
  float*  ce    = (float*)alloc(24*4);
  float*  corr  = (float*)alloc(24*4);
  if (off > ws_size) return;

  const int NS = 192;
  const int BIG = 1 << 30;
  const size_t statsB = 2*64*2*8;

  // ---- L1: 3->32 @128, pool->64, out actA
  hipMemsetAsync(stats, 0, statsB, stream);
  conv_stats_tiled<3,32,128,32,16><<<dim3(16,2,288),256,0,stream>>>(
      support_x, query_x, 192, w1, stats, NS);
  bn_finalize<<<1,128,0,stream>>>(stats, g1, b1, scl, shf, 32,
      192.0*128*128, 96.0*128*128);
  conv_apply_tiled<3,32,128,32,16><<<dim3(16,2,288),256,0,stream>>>(
      support_x, query_x, 192, w1, scl, shf, actA, NS);

  // ---- L2: 32->64 @64, pool->32, out actB
  hipMemsetAsync(stats, 0, statsB, stream);
  conv_stats_tiled<32,64,64,32,16><<<dim3(4,4,288),256,0,stream>>>(
      actA, actA, BIG, w2, stats, NS);
  bn_finalize<<<1,128,0,stream>>>(stats, g2, b2, scl, shf, 64,
      192.0*64*64, 96.0*64*64);
  conv_apply_tiled<32,64,64,32,16><<<dim3(4,4,288),256,0,stream>>>(
      actA, actA, BIG, w2, scl, shf, actB, NS);

  // ---- L3: 64->64 @32, pool->16, out actA (w_rest[0])
  hipMemsetAsync(stats, 0, statsB, stream);
  conv_stats_tiled<64,64,32,32,16><<<dim3(1,4,288),256,0,stream>>>(
      actB, actB, BIG, wr + 0*36864, stats, NS);
  bn_finalize<<<1,128,0,stream>>>(stats, gr + 0*64, br + 0*64, scl, shf, 64,
      192.0*32*32, 96.0*32*32);
  conv_apply_tiled<64,64,32,32,16><<<dim3(1,4,288),256,0,stream>>>(
      actB, actB, BIG, wr + 0*36864, scl, shf, actA, NS);

  // ---- L4: 64->64 @16, pool->8, out actB (w_rest[1])
  hipMemsetAsync(stats, 0, statsB, stream);
  conv_stats_tiled<64,64,16,16,16><<<dim3(1,4,288),64,0,stream>>>(
      actA, actA, BIG, wr + 1*36864, stats, NS);
  bn_finalize<<<1,128,0,stream>>>(stats, gr + 1*64, br + 1*64, scl, shf, 64,
      192.0*16*16, 96.0*16*16);
  conv_apply_tiled<64,64,16,16,16><<<dim3(1,4,288),64,0,stream>>>(
      actA, actA, BIG, wr + 1*36864, scl, shf, actB, NS);

  // ---- L5: 64->64 @8, pool->4, out actA (w_rest[2])
  hipMemsetAsync(stats, 0, statsB, stream);
  conv_stats_v2<64,64,8><<<dim3(1,64,288),256,0,stream>>>(
      actB, actB, BIG, wr + 2*36864, stats, NS);
  bn_finalize<<<1,128,0,stream>>>(stats, gr + 2*64, br + 2*64, scl, shf, 64,
      192.0*8*8, 96.0*8*8);
  conv_apply_v2<64,64,8><<<dim3(1,64,288),256,0,stream>>>(
      actB, actB, BIG, wr + 2*36864, scl, shf, actA, NS);

  // ---- L6: 64->64 @4, pool->2, out actB = feat [288,256] (w_rest[3])
  hipMemsetAsync(stats, 0, statsB, stream);
  conv_stats_v2<64,64,4><<<dim3(1,64,288),256,0,stream>>>(
      actA, actA, BIG, wr + 3*36864, stats, NS);
  bn_finalize<<<1,128,0,stream>>>(stats, gr + 3*64, br + 3*64, scl, shf, 64,
      192.0*4*4, 96.0*4*4);
  conv_apply_v2<64,64,4><<<dim3(1,64,288),256,0,stream>>>(
      actA, actA, BIG, wr + 3*36864, scl, shf, actB, NS);

  // ---- head
  float* feat = actB;
  graph_means<<<72,256,0,stream>>>(feat, s_cat, p_cat);
  hipMemsetAsync(nsum, 0, 192*4, stream);
  hipMemsetAsync(ncnt, 0, 192*4, stream);
  edge_cos<<<768,64,0,stream>>>(feat, s_ei, nsum, ncnt, 768);
  cos_loss_k<<<1,64,0,stream>>>(nsum, ncnt, cosl);
  pd_out<<<24,256,0,stream>>>(s_cat, p_cat, s_y, q_y, ce, corr);
  final_k<<<1,64,0,stream>>>(ce, corr, cosl, (float*)d_out);
}

// Round 7
// 3306.137 us; speedup vs baseline: 10.2011x; 1.8648x over previous
//
#include <hip/hip_runtime.h>
#include <hip/hip_bf16.h>
#include <cstdint>
#include <cstddef>

// Inputs all float32. R6 post-mortem: tiny layers (L5 H=8, L6 H=4) dominated
// (4 x 1.14 ms): naive per-pixel kernels left 94-98% of lanes idle after the
// early exit. R7: conv_small -- one block/image, 256 threads = 64 oc x 4
// position groups, full input plane in LDS, all lanes active (logic validated
// in R2/R3 cross-check).

// ---------------------------------------------------------------------------
// Tiled conv 3x3 SAME (+BN+ReLU+maxpool | +stats). L1-L4.
// Block: (TS/2)^2 threads; each thread owns one 2x2 conv quad x OCG ocs.
// ---------------------------------------------------------------------------
template<int IC, int OC, int H, int TS, int OCG>
__global__ __launch_bounds__(TS*TS/4)
void conv_apply_tiled(const float* __restrict__ inA, const float* __restrict__ inB,
                      int nSplit, const float* __restrict__ W,
                      const float* __restrict__ scale, const float* __restrict__ shift,
                      float* __restrict__ out, int nSupport)
{
  constexpr int TH = TS/2;
  constexpr int NT = TH*TH;
  constexpr int TILES = H/TS;
  const int tid = threadIdx.x;
  const int n   = blockIdx.z;
  const int ocg = blockIdx.y;
  const int ty0 = (blockIdx.x / TILES) * TS;
  const int tx0 = (blockIdx.x % TILES) * TS;

  const float* in = (n < nSplit) ? inA + (size_t)n*IC*H*H
                                 : inB + (size_t)(n - nSplit)*IC*H*H;

  __shared__ float sIn[(TS+2)*(TS+2)];
  __shared__ float sW[9*OCG];

  float acc[4][OCG];
  #pragma unroll
  for (int i = 0; i < 4; ++i)
    #pragma unroll
    for (int o = 0; o < OCG; ++o) acc[i][o] = 0.f;

  const int tx = tid % TH, ty = tid / TH;
  const int iy = 2*ty, ix = 2*tx;

  for (int ic = 0; ic < IC; ++ic) {
    const float* ip = in + (size_t)ic*H*H;
    for (int i = tid; i < (TS+2)*(TS+2); i += NT) {
      int r = i/(TS+2), c = i%(TS+2);
      int gy = ty0 + r - 1, gx = tx0 + c - 1;
      float v = 0.f;
      if (gy >= 0 && gy < H && gx >= 0 && gx < H) v = ip[gy*H + gx];
      sIn[i] = v;
    }
    for (int i = tid; i < 9*OCG; i += NT) {
      int k = i / OCG, oc = i % OCG;
      sW[i] = W[((size_t)(ocg*OCG + oc)*IC + ic)*9 + k];
    }
    __syncthreads();
    #pragma unroll
    for (int kh = 0; kh < 3; ++kh) {
      #pragma unroll
      for (int kw = 0; kw < 3; ++kw) {
        float x00 = sIn[(iy+kh  )*(TS+2) + ix+kw  ];
        float x01 = sIn[(iy+kh  )*(TS+2) + ix+kw+1];
        float x10 = sIn[(iy+kh+1)*(TS+2) + ix+kw  ];
        float x11 = sIn[(iy+kh+1)*(TS+2) + ix+kw+1];
        const float* wk = &sW[(kh*3+kw)*OCG];
        #pragma unroll
        for (int oc = 0; oc < OCG; ++oc) {
          float wv = wk[oc];
          acc[0][oc] = fmaf(x00, wv, acc[0][oc]);
          acc[1][oc] = fmaf(x01, wv, acc[1][oc]);
          acc[2][oc] = fmaf(x10, wv, acc[2][oc]);
          acc[3][oc] = fmaf(x11, wv, acc[3][oc]);
        }
      }
    }
    __syncthreads();
  }

  const int g = (n < nSupport) ? 0 : 1;
  #pragma unroll
  for (int oc = 0; oc < OCG; ++oc) {
    const int ocGl = ocg*OCG + oc;
    const float s = scale[g*OC + ocGl];
    const float t = shift[g*OC + ocGl];
    float v0 = fmaxf(fmaf(acc[0][oc], s, t), 0.f);
    float v1 = fmaxf(fmaf(acc[1][oc], s, t), 0.f);
    float v2 = fmaxf(fmaf(acc[2][oc], s, t), 0.f);
    float v3 = fmaxf(fmaf(acc[3][oc], s, t), 0.f);
    float m = fmaxf(fmaxf(v0, v1), fmaxf(v2, v3));
    int py = ty0/2 + ty, px = tx0/2 + tx;
    out[(((size_t)n*OC + ocGl)*(H/2) + py)*(H/2) + px] = m;
  }
}

template<int IC, int OC, int H, int TS, int OCG>
__global__ __launch_bounds__(TS*TS/4)
void conv_stats_tiled(const float* __restrict__ inA, const float* __restrict__ inB,
                      int nSplit, const float* __restrict__ W,
                      double* __restrict__ stats, int nSupport)
{
  constexpr int TH = TS/2;
  constexpr int NT = TH*TH;
  constexpr int NW = NT/64;
  constexpr int TILES = H/TS;
  const int tid = threadIdx.x;
  const int n   = blockIdx.z;
  const int ocg = blockIdx.y;
  const int ty0 = (blockIdx.x / TILES) * TS;
  const int tx0 = (blockIdx.x % TILES) * TS;

  const float* in = (n < nSplit) ? inA + (size_t)n*IC*H*H
                                 : inB + (size_t)(n - nSplit)*IC*H*H;

  __shared__ float sIn[(TS+2)*(TS+2)];
  __shared__ float sW[9*OCG];
  __shared__ float sSum[NW][OCG], sSsq[NW][OCG];

  float acc[4][OCG];
  #pragma unroll
  for (int i = 0; i < 4; ++i)
    #pragma unroll
    for (int o = 0; o < OCG; ++o) acc[i][o] = 0.f;

  const int tx = tid % TH, ty = tid / TH;
  const int iy = 2*ty, ix = 2*tx;

  for (int ic = 0; ic < IC; ++ic) {
    const float* ip = in + (size_t)ic*H*H;
    for (int i = tid; i < (TS+2)*(TS+2); i += NT) {
      int r = i/(TS+2), c = i%(TS+2);
      int gy = ty0 + r - 1, gx = tx0 + c - 1;
      float v = 0.f;
      if (gy >= 0 && gy < H && gx >= 0 && gx < H) v = ip[gy*H + gx];
      sIn[i] = v;
    }
    for (int i = tid; i < 9*OCG; i += NT) {
      int k = i / OCG, oc = i % OCG;
      sW[i] = W[((size_t)(ocg*OCG + oc)*IC + ic)*9 + k];
    }
    __syncthreads();
    #pragma unroll
    for (int kh = 0; kh < 3; ++kh) {
      #pragma unroll
      for (int kw = 0; kw < 3; ++kw) {
        float x00 = sIn[(iy+kh  )*(TS+2) + ix+kw  ];
        float x01 = sIn[(iy+kh  )*(TS+2) + ix+kw+1];
        float x10 = sIn[(iy+kh+1)*(TS+2) + ix+kw  ];
        float x11 = sIn[(iy+kh+1)*(TS+2) + ix+kw+1];
        const float* wk = &sW[(kh*3+kw)*OCG];
        #pragma unroll
        for (int oc = 0; oc < OCG; ++oc) {
          float wv = wk[oc];
          acc[0][oc] = fmaf(x00, wv, acc[0][oc]);
          acc[1][oc] = fmaf(x01, wv, acc[1][oc]);
          acc[2][oc] = fmaf(x10, wv, acc[2][oc]);
          acc[3][oc] = fmaf(x11, wv, acc[3][oc]);
        }
      }
    }
    __syncthreads();
  }

  const int lane = tid & 63, wid = tid >> 6;
  #pragma unroll
  for (int oc = 0; oc < OCG; ++oc) {
    float ls = acc[0][oc] + acc[1][oc] + acc[2][oc] + acc[3][oc];
    float lq = acc[0][oc]*acc[0][oc] + acc[1][oc]*acc[1][oc]
             + acc[2][oc]*acc[2][oc] + acc[3][oc]*acc[3][oc];
    #pragma unroll
    for (int off = 32; off > 0; off >>= 1) {
      ls += __shfl_down(ls, off);
      lq += __shfl_down(lq, off);
    }
    if (lane == 0) { sSum[wid][oc] = ls; sSsq[wid][oc] = lq; }
  }
  __syncthreads();
  if (tid < OCG) {
    float S = 0.f, Q = 0.f;
    #pragma unroll
    for (int w = 0; w < NW; ++w) { S += sSum[w][tid]; Q += sSsq[w][tid]; }
    const int g = (n < nSupport) ? 0 : 1;
    const int ocGl = ocg*OCG + tid;
    atomicAdd(&stats[(g*OC + ocGl)*2 + 0], (double)S);
    atomicAdd(&stats[(g*OC + ocGl)*2 + 1], (double)Q);
  }
}

// ---------------------------------------------------------------------------
// Tiny layers (L5 H=8, L6 H=4), IC=OC=64, one image per block, 256 threads =
// 64 oc x 4 position groups; all lanes active. Input plane fully in LDS;
// weights staged in 16-ic chunks. Logic cross-validated in R2/R3.
// ---------------------------------------------------------------------------
template<int H, bool APPLY>
__global__ __launch_bounds__(256)
void conv_small(const float* __restrict__ in, const float* __restrict__ W,
                const float* __restrict__ scale, const float* __restrict__ shift,
                double* __restrict__ stats, float* __restrict__ out, int nSupport)
{
  constexpr int HW = H*H;
  constexpr int NACC = (H == 8) ? 16 : 4;
  constexpr int SC = (H == 4) ? 64*16 : 1;
  const int tid = threadIdx.x;
  const int n  = blockIdx.x;
  const int oc = tid & 63;
  const int q  = tid >> 6;

  __shared__ float sX[64*HW];
  __shared__ float sWc[16*9*64];   // [ic_local][k][oc]
  __shared__ float sS[256];
  __shared__ float sQ[256];
  __shared__ float sC[SC];

  for (int i = tid; i < 64*HW; i += 256) sX[i] = in[(size_t)n*64*HW + i];

  float acc[NACC];
  #pragma unroll
  for (int i = 0; i < NACC; ++i) acc[i] = 0.f;

  const int ry = (H == 8) ? 4*(q >> 1) : 0;
  const int rx = (H == 8) ? 4*(q & 1)  : 0;

  for (int ch = 0; ch < 4; ++ch) {
    __syncthreads();   // protects sX (first iter) and sWc reuse (later iters)
    for (int i = tid; i < 16*9*64; i += 256) {
      int o = i / 144, r = i % 144;
      int il = r / 9, k = r % 9;
      sWc[il*576 + k*64 + o] = W[((size_t)o*64 + (ch*16 + il))*9 + k];
    }
    __syncthreads();
    for (int il = 0; il < 16; ++il) {
      int ic = ch*16 + il;
      if (H == 8) {
        float rin[6][6];
        #pragma unroll
        for (int r = 0; r < 6; ++r) {
          int y = ry + r - 1;
          #pragma unroll
          for (int c = 0; c < 6; ++c) {
            int x = rx + c - 1;
            rin[r][c] = (y >= 0 && y < H && x >= 0 && x < H) ? sX[ic*HW + y*H + x] : 0.f;
          }
        }
        #pragma unroll
        for (int kh = 0; kh < 3; ++kh)
          #pragma unroll
          for (int kw = 0; kw < 3; ++kw) {
            float wv = sWc[il*576 + (kh*3+kw)*64 + oc];
            #pragma unroll
            for (int py = 0; py < 4; ++py)
              #pragma unroll
              for (int px = 0; px < 4; ++px)
                acc[py*4+px] = fmaf(wv, rin[py+kh][px+kw], acc[py*4+px]);
          }
      } else {
        float rin[3][6];
        #pragma unroll
        for (int r = 0; r < 3; ++r) {
          int y = q + r - 1;
          #pragma unroll
          for (int c = 0; c < 6; ++c) {
            int x = c - 1;
            rin[r][c] = (y >= 0 && y < H && x >= 0 && x < H) ? sX[ic*HW + y*H + x] : 0.f;
          }
        }
        #pragma unroll
        for (int kh = 0; kh < 3; ++kh)
          #pragma unroll
          for (int kw = 0; kw < 3; ++kw) {
            float wv = sWc[il*576 + (kh*3+kw)*64 + oc];
            #pragma unroll
            for (int px = 0; px < 4; ++px)
              acc[px] = fmaf(wv, rin[kh][px+kw], acc[px]);
          }
      }
    }
  }

  const int g = (n < nSupport) ? 0 : 1;
  if (APPLY) {
    float s = scale[g*64 + oc];
    float t = shift[g*64 + oc];
    if (H == 8) {
      const int py0 = ry/2, px0 = rx/2;
      #pragma unroll
      for (int pj = 0; pj < 2; ++pj)
        #pragma unroll
        for (int pi = 0; pi < 2; ++pi) {
          float v0 = fmaxf(fmaf(acc[(2*pj  )*4 + 2*pi  ], s, t), 0.f);
          float v1 = fmaxf(fmaf(acc[(2*pj  )*4 + 2*pi+1], s, t), 0.f);
          float v2 = fmaxf(fmaf(acc[(2*pj+1)*4 + 2*pi  ], s, t), 0.f);
          float v3 = fmaxf(fmaf(acc[(2*pj+1)*4 + 2*pi+1], s, t), 0.f);
          out[(((size_t)n*64 + oc)*4 + (py0+pj))*4 + (px0+pi)] =
              fmaxf(fmaxf(v0, v1), fmaxf(v2, v3));
        }
    } else {
      #pragma unroll
      for (int px = 0; px < 4; ++px)
        sC[oc*16 + q*4 + px] = fmaxf(fmaf(acc[px], s, t), 0.f);
      __syncthreads();
      int oc2 = tid & 63, pj = (tid >> 6) & 1, pi = (tid >> 7) & 1;
      float m = fmaxf(
          fmaxf(sC[oc2*16 + (2*pj  )*4 + 2*pi], sC[oc2*16 + (2*pj  )*4 + 2*pi+1]),
          fmaxf(sC[oc2*16 + (2*pj+1)*4 + 2*pi], sC[oc2*16 + (2*pj+1)*4 + 2*pi+1]));
      out[(((size_t)n*64 + oc2)*2 + pj)*2 + pi] = m;
    }
  } else {
    float ls = 0.f, lq = 0.f;
    #pragma unroll
    for (int i = 0; i < NACC; ++i) { ls += acc[i]; lq += acc[i]*acc[i]; }
    sS[tid] = ls; sQ[tid] = lq;
    __syncthreads();
    if (tid < 64) {
      float S = sS[tid] + sS[tid+64] + sS[tid+128] + sS[tid+192];
      float Q = sQ[tid] + sQ[tid+64] + sQ[tid+128] + sQ[tid+192];
      atomicAdd(&stats[(g*64 + tid)*2 + 0], (double)S);
      atomicAdd(&stats[(g*64 + tid)*2 + 1], (double)Q);
    }
  }
}

// ---------------------------------------------------------------------------
__global__ void bn_finalize(const double* __restrict__ stats,
                            const float* __restrict__ gamma, const float* __restrict__ beta,
                            float* __restrict__ scale, float* __restrict__ shift,
                            int OC, double cnt0, double cnt1)
{
  int i = threadIdx.x;
  if (i < 2*OC) {
    int oc = i % OC;
    double cnt = (i < OC) ? cnt0 : cnt1;
    double mean = stats[i*2 + 0] / cnt;
    double var  = stats[i*2 + 1] / cnt - mean*mean;
    double inv  = 1.0 / sqrt(var + 1e-5);
    double g = (double)gamma[oc];
    double b = (double)beta[oc];
    scale[i] = (float)(g * inv);
    shift[i] = (float)(b - mean * g * inv);
  }
}

// ---------------------------------------------------------------------------
__global__ void graph_means(const float* __restrict__ feat,
                            float* __restrict__ s_cat, float* __restrict__ p_cat)
{
  int g = blockIdx.x, d = threadIdx.x;
  if (g < 48) {
    float v = 0.f;
    for (int i = 0; i < 4; ++i) v += feat[(size_t)(4*g + i)*256 + d];
    s_cat[g*256 + d] = v * 0.25f;
  } else {
    int q = g - 48;
    float v = 0.f;
    for (int i = 0; i < 4; ++i) v += feat[(size_t)(192 + 4*q + i)*256 + d];
    p_cat[q*256 + d] = v * 0.25f;
  }
}

__global__ void edge_cos(const float* __restrict__ feat, const int* __restrict__ ei,
                         float* __restrict__ nsum, float* __restrict__ ncnt, int nEdges)
{
  int e = blockIdx.x, lane = threadIdx.x;
  int src = ei[e], dst = ei[nEdges + e];
  float dot = 0.f, nj = 0.f, ni = 0.f;
  for (int j = lane; j < 256; j += 64) {
    float a = feat[(size_t)src*256 + j];
    float b = feat[(size_t)dst*256 + j];
    dot += a*b; nj += a*a; ni += b*b;
  }
  for (int off = 32; off > 0; off >>= 1) {
    dot += __shfl_down(dot, off);
    nj  += __shfl_down(nj,  off);
    ni  += __shfl_down(ni,  off);
  }
  if (lane == 0) {
    float denom = fmaxf(sqrtf(nj)*sqrtf(ni), 1e-6f);
    atomicAdd(&nsum[dst], dot/denom);
    atomicAdd(&ncnt[dst], 1.f);
  }
}

__global__ void cos_loss_k(const float* __restrict__ nsum, const float* __restrict__ ncnt,
                           float* __restrict__ cosloss)
{
  int g = threadIdx.x;
  float v = 0.f;
  if (g < 48) {
    float gm = 0.f;
    for (int i = 0; i < 4; ++i) {
      int nd = 4*g + i;
      gm += nsum[nd] / fmaxf(ncnt[nd], 1.f);
    }
    gm *= 0.25f;
    v = (gm - 1.f)*(gm - 1.f);
  }
  for (int off = 32; off > 0; off >>= 1) v += __shfl_down(v, off);
  if (g == 0) cosloss[0] = v;
}

__global__ void pd_out(const float* __restrict__ s_cat, const float* __restrict__ p_cat,
                       const int* __restrict__ support_y, const int* __restrict__ query_y,
                       float* __restrict__ ce, float* __restrict__ correct)
{
  const int q = blockIdx.x;
  const int tid = threadIdx.x, lane = tid & 63, wid = tid >> 6;
  __shared__ float sP[48];
  __shared__ float sOut[24];
  float pv[4];
  #pragma unroll
  for (int j = 0; j < 4; ++j) pv[j] = p_cat[(size_t)q*256 + lane + 64*j];
  for (int s = wid*12; s < wid*12 + 12; ++s) {
    float d2 = 0.f;
    #pragma unroll
    for (int j = 0; j < 4; ++j) {
      float diff = pv[j] - s_cat[(size_t)s*256 + lane + 64*j];
      d2 += diff*diff;
    }
    for (int off = 32; off > 0; off >>= 1) d2 += __shfl_down(d2, off);
    if (lane == 0) sP[s] = expf(-d2);
  }
  __syncthreads();
  if (tid < 24) {
    int c = tid; float sum = 0.f; int cnt = 0;
    for (int s = 0; s < 48; ++s)
      if (support_y[s] == c) { sum += sP[s]; ++cnt; }
    sOut[c] = sum / fmaxf((float)cnt, 1.f);
  }
  __syncthreads();
  if (tid == 0) {
    float m = sOut[0]; int am = 0;
    for (int c = 1; c < 24; ++c) if (sOut[c] > m) { m = sOut[c]; am = c; }
    float lse = 0.f;
    for (int c = 0; c < 24; ++c) lse += expf(sOut[c] - m);
    lse = m + logf(lse);
    int y = query_y[q];
    ce[q] = lse - sOut[y];
    correct[q] = (am == y) ? 1.f : 0.f;
  }
}

__global__ void final_k(const float* __restrict__ ce, const float* __restrict__ correct,
                        const float* __restrict__ cosloss, float* __restrict__ out)
{
  if (threadIdx.x == 0) {
    float s = 0.f, a = 0.f;
    for (int qq = 0; qq < 24; ++qq) { s += ce[qq]; a += correct[qq]; }
    float atten = ce[5];
    float rest  = (s - atten) / 23.f;
    float cl = cosloss[0];
    out[0] = atten + rest + cl;
    out[1] = a;
    out[2] = cl;
    out[3] = atten;
    out[4] = rest;
  }
}

// ---------------------------------------------------------------------------
extern "C" void kernel_launch(void* const* d_in, const int* in_sizes, int n_in,
                              void* d_out, int out_size, void* d_ws, size_t ws_size,
                              hipStream_t stream)
{
  const float* support_x = (const float*)d_in[0];
  const float* query_x   = (const float*)d_in[1];
  const int*   s_ei      = (const int*)d_in[2];
  const int*   s_y       = (const int*)d_in[6];
  const int*   q_y       = (const int*)d_in[7];
  const float* w1 = (const float*)d_in[8];
  const float* g1 = (const float*)d_in[9];
  const float* b1 = (const float*)d_in[10];
  const float* w2 = (const float*)d_in[11];
  const float* g2 = (const float*)d_in[12];
  const float* b2 = (const float*)d_in[13];
  const float* wr = (const float*)d_in[14];
  const float* gr = (const float*)d_in[15];
  const float* br = (const float*)d_in[16];
  (void)in_sizes; (void)n_in; (void)out_size;

  char* ws = (char*)d_ws;
  size_t off = 0;
  auto alloc = [&](size_t bytes) -> char* {
    char* p = ws + off;
    off = (off + bytes + 255) & ~(size_t)255;
    return p;
  };
  float*  actA  = (float*)alloc((size_t)288*32*64*64*4);   // 151 MB ping
  float*  actB  = (float*)alloc((size_t)288*64*32*32*4);   // 75.5 MB pong
  double* stats = (double*)alloc(2*64*2*8);
  float*  scl   = (float*)alloc(2*64*4);
  float*  shf   = (float*)alloc(2*64*4);
  float*  s_cat = (float*)alloc(48*256*4);
  float*  p_cat = (float*)alloc(24*256*4);
  float*  nsum  = (float*)alloc(192*4);
  float*  ncnt  = (float*)alloc(192*4);
  float*  cosl  = (float*)alloc(256);
  float*  ce    = (float*)alloc(24*4);
  float*  corr  = (float*)alloc(24*4);
  if (off > ws_size) return;

  const int NS = 192;
  const int BIG = 1 << 30;
  const size_t statsB = 2*64*2*8;

  // ---- L1: 3->32 @128, pool->64, out actA
  hipMemsetAsync(stats, 0, statsB, stream);
  conv_stats_tiled<3,32,128,32,16><<<dim3(16,2,288),256,0,stream>>>(
      support_x, query_x, 192, w1, stats, NS);
  bn_finalize<<<1,128,0,stream>>>(stats, g1, b1, scl, shf, 32,
      192.0*128*128, 96.0*128*128);
  conv_apply_tiled<3,32,128,32,16><<<dim3(16,2,288),256,0,stream>>>(
      support_x, query_x, 192, w1, scl, shf, actA, NS);

  // ---- L2: 32->64 @64, pool->32, out actB
  hipMemsetAsync(stats, 0, statsB, stream);
  conv_stats_tiled<32,64,64,32,16><<<dim3(4,4,288),256,0,stream>>>(
      actA, actA, BIG, w2, stats, NS);
  bn_finalize<<<1,128,0,stream>>>(stats, g2, b2, scl, shf, 64,
      192.0*64*64, 96.0*64*64);
  conv_apply_tiled<32,64,64,32,16><<<dim3(4,4,288),256,0,stream>>>(
      actA, actA, BIG, w2, scl, shf, actB, NS);

  // ---- L3: 64->64 @32, pool->16, out actA (w_rest[0])
  hipMemsetAsync(stats, 0, statsB, stream);
  conv_stats_tiled<64,64,32,32,16><<<dim3(1,4,288),256,0,stream>>>(
      actB, actB, BIG, wr + 0*36864, stats, NS);
  bn_finalize<<<1,128,0,stream>>>(stats, gr + 0*64, br + 0*64, scl, shf, 64,
      192.0*32*32, 96.0*32*32);
  conv_apply_tiled<64,64,32,32,16><<<dim3(1,4,288),256,0,stream>>>(
      actB, actB, BIG, wr + 0*36864, scl, shf, actA, NS);

  // ---- L4: 64->64 @16, pool->8, out actB (w_rest[1])
  hipMemsetAsync(stats, 0, statsB, stream);
  conv_stats_tiled<64,64,16,16,16><<<dim3(1,4,288),64,0,stream>>>(
      actA, actA, BIG, wr + 1*36864, stats, NS);
  bn_finalize<<<1,128,0,stream>>>(stats, gr + 1*64, br + 1*64, scl, shf, 64,
      192.0*16*16, 96.0*16*16);
  conv_apply_tiled<64,64,16,16,16><<<dim3(1,4,288),64,0,stream>>>(
      actA, actA, BIG, wr + 1*36864, scl, shf, actB, NS);

  // ---- L5: 64->64 @8, pool->4, out actA (w_rest[2])
  hipMemsetAsync(stats, 0, statsB, stream);
  conv_small<8,false><<<288,256,0,stream>>>(
      actB, wr + 2*36864, nullptr, nullptr, stats, nullptr, NS);
  bn_finalize<<<1,128,0,stream>>>(stats, gr + 2*64, br + 2*64, scl, shf, 64,
      192.0*8*8, 96.0*8*8);
  conv_small<8,true><<<288,256,0,stream>>>(
      actB, wr + 2*36864, scl, shf, nullptr, actA, NS);

  // ---- L6: 64->64 @4, pool->2, out actB = feat [288,256] (w_rest[3])
  hipMemsetAsync(stats, 0, statsB, stream);
  conv_small<4,false><<<288,256,0,stream>>>(
      actA, wr + 3*36864, nullptr, nullptr, stats, nullptr, NS);
  bn_finalize<<<1,128,0,stream>>>(stats, gr + 3*64, br + 3*64, scl, shf, 64,
      192.0*4*4, 96.0*4*4);
  conv_small<4,true><<<288,256,0,stream>>>(
      actA, wr + 3*36864, scl, shf, nullptr, actB, NS);

  // ---- head
  float* feat = actB;
  graph_means<<<72,256,0,stream>>>(feat, s_cat, p_cat);
  hipMemsetAsync(nsum, 0, 192*4, stream);
  hipMemsetAsync(ncnt, 0, 192*4, stream);
  edge_cos<<<768,64,0,stream>>>(feat, s_ei, nsum, ncnt, 768);
  cos_loss_k<<<1,64,0,stream>>>(nsum, ncnt, cosl);
  pd_out<<<24,256,0,stream>>>(s_cat, p_cat, s_y, q_y, ce, corr);
  final_k<<<1,64,0,stream>>>(ce, corr, cosl, (float*)d_out);
}

// Round 8
// 2635.955 us; speedup vs baseline: 12.7947x; 1.2542x over previous
//
#include <hip/hip_runtime.h>
#include <hip/hip_bf16.h>
#include <cstdint>
#include <cstddef>

// R7 post-mortem: inner loop issued 180 ds_read per 576 FMA (37% of vector
// roofline). R8: weights via wave-uniform scalar loads (SGPR operand to
// v_fma), x-taps via a 4x4 register window (ds_read_b64 pairs), L4 occupancy
// fix (OCG=4). Same math, same summation structure per accumulator.

// ---------------------------------------------------------------------------
// Unified tiled conv 3x3 SAME: APPLY ? BN+ReLU+maxpool2 : per-(group,oc)
// sum/sumsq stats. Block: (TS/2)^2 threads; each thread owns one 2x2 conv
// quad x OCG ocs. grid = (tiles^2, OC/OCG, N).
// ---------------------------------------------------------------------------
template<int IC, int OC, int H, int TS, int OCG, bool APPLY>
__global__ __launch_bounds__(TS*TS/4)
void conv_tiled(const float* __restrict__ inA, const float* __restrict__ inB,
                int nSplit, const float* __restrict__ W,
                const float* __restrict__ scale, const float* __restrict__ shift,
                double* __restrict__ stats, float* __restrict__ out, int nSupport)
{
  constexpr int TH = TS/2;
  constexpr int NT = TH*TH;
  constexpr int NW = (NT+63)/64;
  constexpr int TILES = H/TS;
  const int tid = threadIdx.x;
  const int n   = blockIdx.z;
  const int ocg = blockIdx.y;
  const int ty0 = (blockIdx.x / TILES) * TS;
  const int tx0 = (blockIdx.x % TILES) * TS;

  const float* in = (n < nSplit) ? inA + (size_t)n*IC*H*H
                                 : inB + (size_t)(n - nSplit)*IC*H*H;
  const float* Wb = W + (size_t)(ocg*OCG)*IC*9;   // uniform per block

  __shared__ float sIn[(TS+2)*(TS+2)];
  __shared__ float sSum[NW][OCG], sSsq[NW][OCG];  // tiny; unused in APPLY

  float acc[4][OCG];
  #pragma unroll
  for (int i = 0; i < 4; ++i)
    #pragma unroll
    for (int o = 0; o < OCG; ++o) acc[i][o] = 0.f;

  const int tx = tid % TH, ty = tid / TH;
  const int iy = 2*ty, ix = 2*tx;

  for (int ic = 0; ic < IC; ++ic) {
    const float* ip = in + (size_t)ic*H*H;
    for (int i = tid; i < (TS+2)*(TS+2); i += NT) {
      int r = i/(TS+2), c = i%(TS+2);
      int gy = ty0 + r - 1, gx = tx0 + c - 1;
      float v = 0.f;
      if (gy >= 0 && gy < H && gx >= 0 && gx < H) v = ip[gy*H + gx];
      sIn[i] = v;
    }
    __syncthreads();

    // 4x4 register window: rows iy..iy+3, cols ix..ix+3 (ix even -> b64 ok)
    float xr[4][4];
    #pragma unroll
    for (int r = 0; r < 4; ++r)
      #pragma unroll
      for (int c = 0; c < 4; ++c)
        xr[r][c] = sIn[(iy+r)*(TS+2) + ix + c];

    #pragma unroll
    for (int oc = 0; oc < OCG; ++oc) {
      const float* wp = Wb + (size_t)oc*IC*9 + ic*9;   // uniform -> s_load
      float w[9];
      #pragma unroll
      for (int k = 0; k < 9; ++k) w[k] = wp[k];
      #pragma unroll
      for (int kh = 0; kh < 3; ++kh) {
        #pragma unroll
        for (int kw = 0; kw < 3; ++kw) {
          const float wv = w[kh*3 + kw];
          acc[0][oc] = fmaf(xr[kh  ][kw  ], wv, acc[0][oc]);
          acc[1][oc] = fmaf(xr[kh  ][kw+1], wv, acc[1][oc]);
          acc[2][oc] = fmaf(xr[kh+1][kw  ], wv, acc[2][oc]);
          acc[3][oc] = fmaf(xr[kh+1][kw+1], wv, acc[3][oc]);
        }
      }
    }
    __syncthreads();
  }

  const int g = (n < nSupport) ? 0 : 1;
  if constexpr (APPLY) {
    #pragma unroll
    for (int oc = 0; oc < OCG; ++oc) {
      const int ocGl = ocg*OCG + oc;
      const float s = scale[g*OC + ocGl];
      const float t = shift[g*OC + ocGl];
      float v0 = fmaxf(fmaf(acc[0][oc], s, t), 0.f);
      float v1 = fmaxf(fmaf(acc[1][oc], s, t), 0.f);
      float v2 = fmaxf(fmaf(acc[2][oc], s, t), 0.f);
      float v3 = fmaxf(fmaf(acc[3][oc], s, t), 0.f);
      float m = fmaxf(fmaxf(v0, v1), fmaxf(v2, v3));
      int py = ty0/2 + ty, px = tx0/2 + tx;
      out[(((size_t)n*OC + ocGl)*(H/2) + py)*(H/2) + px] = m;
    }
  } else {
    const int lane = tid & 63, wid = tid >> 6;
    #pragma unroll
    for (int oc = 0; oc < OCG; ++oc) {
      float ls = acc[0][oc] + acc[1][oc] + acc[2][oc] + acc[3][oc];
      float lq = acc[0][oc]*acc[0][oc] + acc[1][oc]*acc[1][oc]
               + acc[2][oc]*acc[2][oc] + acc[3][oc]*acc[3][oc];
      #pragma unroll
      for (int off = 32; off > 0; off >>= 1) {
        ls += __shfl_down(ls, off);
        lq += __shfl_down(lq, off);
      }
      if (lane == 0) { sSum[wid][oc] = ls; sSsq[wid][oc] = lq; }
    }
    __syncthreads();
    if (tid < OCG) {
      float S = 0.f, Q = 0.f;
      #pragma unroll
      for (int w = 0; w < NW; ++w) { S += sSum[w][tid]; Q += sSsq[w][tid]; }
      const int ocGl = ocg*OCG + tid;
      atomicAdd(&stats[(g*OC + ocGl)*2 + 0], (double)S);
      atomicAdd(&stats[(g*OC + ocGl)*2 + 1], (double)Q);
    }
  }
}

// ---------------------------------------------------------------------------
// Tiny layers (L5 H=8, L6 H=4): one block/image, 256 threads = 64 oc x 4
// position groups, input plane in LDS. Validated R2/R3/R7.
// ---------------------------------------------------------------------------
template<int H, bool APPLY>
__global__ __launch_bounds__(256)
void conv_small(const float* __restrict__ in, const float* __restrict__ W,
                const float* __restrict__ scale, const float* __restrict__ shift,
                double* __restrict__ stats, float* __restrict__ out, int nSupport)
{
  constexpr int HW = H*H;
  constexpr int NACC = (H == 8) ? 16 : 4;
  constexpr int SC = (H == 4) ? 64*16 : 1;
  const int tid = threadIdx.x;
  const int n  = blockIdx.x;
  const int oc = tid & 63;
  const int q  = tid >> 6;

  __shared__ float sX[64*HW];
  __shared__ float sS[256];
  __shared__ float sQ[256];
  __shared__ float sC[SC];

  for (int i = tid; i < 64*HW; i += 256) sX[i] = in[(size_t)n*64*HW + i];
  __syncthreads();

  float acc[NACC];
  #pragma unroll
  for (int i = 0; i < NACC; ++i) acc[i] = 0.f;

  const int ry = (H == 8) ? 4*(q >> 1) : 0;
  const int rx = (H == 8) ? 4*(q & 1)  : 0;

  for (int ic = 0; ic < 64; ++ic) {
    // weights for (oc, ic): 9 scalar-ish loads (oc varies per lane -> vector,
    // but L1-cached and reused across NACC px)
    const float* wp = W + ((size_t)oc*64 + ic)*9;
    float w[9];
    #pragma unroll
    for (int k = 0; k < 9; ++k) w[k] = wp[k];
    if (H == 8) {
      float rin[6][6];
      #pragma unroll
      for (int r = 0; r < 6; ++r) {
        int y = ry + r - 1;
        #pragma unroll
        for (int c = 0; c < 6; ++c) {
          int x = rx + c - 1;
          rin[r][c] = (y >= 0 && y < H && x >= 0 && x < H) ? sX[ic*HW + y*H + x] : 0.f;
        }
      }
      #pragma unroll
      for (int kh = 0; kh < 3; ++kh)
        #pragma unroll
        for (int kw = 0; kw < 3; ++kw) {
          float wv = w[kh*3+kw];
          #pragma unroll
          for (int py = 0; py < 4; ++py)
            #pragma unroll
            for (int px = 0; px < 4; ++px)
              acc[py*4+px] = fmaf(wv, rin[py+kh][px+kw], acc[py*4+px]);
        }
    } else {
      float rin[3][6];
      #pragma unroll
      for (int r = 0; r < 3; ++r) {
        int y = q + r - 1;
        #pragma unroll
        for (int c = 0; c < 6; ++c) {
          int x = c - 1;
          rin[r][c] = (y >= 0 && y < H && x >= 0 && x < H) ? sX[ic*HW + y*H + x] : 0.f;
        }
      }
      #pragma unroll
      for (int kh = 0; kh < 3; ++kh)
        #pragma unroll
        for (int kw = 0; kw < 3; ++kw) {
          float wv = w[kh*3+kw];
          #pragma unroll
          for (int px = 0; px < 4; ++px)
            acc[px] = fmaf(wv, rin[kh][px+kw], acc[px]);
        }
    }
  }

  const int g = (n < nSupport) ? 0 : 1;
  if (APPLY) {
    float s = scale[g*64 + oc];
    float t = shift[g*64 + oc];
    if (H == 8) {
      const int py0 = ry/2, px0 = rx/2;
      #pragma unroll
      for (int pj = 0; pj < 2; ++pj)
        #pragma unroll
        for (int pi = 0; pi < 2; ++pi) {
          float v0 = fmaxf(fmaf(acc[(2*pj  )*4 + 2*pi  ], s, t), 0.f);
          float v1 = fmaxf(fmaf(acc[(2*pj  )*4 + 2*pi+1], s, t), 0.f);
          float v2 = fmaxf(fmaf(acc[(2*pj+1)*4 + 2*pi  ], s, t), 0.f);
          float v3 = fmaxf(fmaf(acc[(2*pj+1)*4 + 2*pi+1], s, t), 0.f);
          out[(((size_t)n*64 + oc)*4 + (py0+pj))*4 + (px0+pi)] =
              fmaxf(fmaxf(v0, v1), fmaxf(v2, v3));
        }
    } else {
      #pragma unroll
      for (int px = 0; px < 4; ++px)
        sC[oc*16 + q*4 + px] = fmaxf(fmaf(acc[px], s, t), 0.f);
      __syncthreads();
      int oc2 = tid & 63, pj = (tid >> 6) & 1, pi = (tid >> 7) & 1;
      float m = fmaxf(
          fmaxf(sC[oc2*16 + (2*pj  )*4 + 2*pi], sC[oc2*16 + (2*pj  )*4 + 2*pi+1]),
          fmaxf(sC[oc2*16 + (2*pj+1)*4 + 2*pi], sC[oc2*16 + (2*pj+1)*4 + 2*pi+1]));
      out[(((size_t)n*64 + oc2)*2 + pj)*2 + pi] = m;
    }
  } else {
    float ls = 0.f, lq = 0.f;
    #pragma unroll
    for (int i = 0; i < NACC; ++i) { ls += acc[i]; lq += acc[i]*acc[i]; }
    sS[tid] = ls; sQ[tid] = lq;
    __syncthreads();
    if (tid < 64) {
      float S = sS[tid] + sS[tid+64] + sS[tid+128] + sS[tid+192];
      float Q = sQ[tid] + sQ[tid+64] + sQ[tid+128] + sQ[tid+192];
      atomicAdd(&stats[(g*64 + tid)*2 + 0], (double)S);
      atomicAdd(&stats[(g*64 + tid)*2 + 1], (double)Q);
    }
  }
}

// ---------------------------------------------------------------------------
__global__ void bn_finalize(const double* __restrict__ stats,
                            const float* __restrict__ gamma, const float* __restrict__ beta,
                            float* __restrict__ scale, float* __restrict__ shift,
                            int OC, double cnt0, double cnt1)
{
  int i = threadIdx.x;
  if (i < 2*OC) {
    int oc = i % OC;
    double cnt = (i < OC) ? cnt0 : cnt1;
    double mean = stats[i*2 + 0] / cnt;
    double var  = stats[i*2 + 1] / cnt - mean*mean;
    double inv  = 1.0 / sqrt(var + 1e-5);
    double g = (double)gamma[oc];
    double b = (double)beta[oc];
    scale[i] = (float)(g * inv);
    shift[i] = (float)(b - mean * g * inv);
  }
}

// ---------------------------------------------------------------------------
__global__ void graph_means(const float* __restrict__ feat,
                            float* __restrict__ s_cat, float* __restrict__ p_cat)
{
  int g = blockIdx.x, d = threadIdx.x;
  if (g < 48) {
    float v = 0.f;
    for (int i = 0; i < 4; ++i) v += feat[(size_t)(4*g + i)*256 + d];
    s_cat[g*256 + d] = v * 0.25f;
  } else {
    int q = g - 48;
    float v = 0.f;
    for (int i = 0; i < 4; ++i) v += feat[(size_t)(192 + 4*q + i)*256 + d];
    p_cat[q*256 + d] = v * 0.25f;
  }
}

__global__ void edge_cos(const float* __restrict__ feat, const int* __restrict__ ei,
                         float* __restrict__ nsum, float* __restrict__ ncnt, int nEdges)
{
  int e = blockIdx.x, lane = threadIdx.x;
  int src = ei[e], dst = ei[nEdges + e];
  float dot = 0.f, nj = 0.f, ni = 0.f;
  for (int j = lane; j < 256; j += 64) {
    float a = feat[(size_t)src*256 + j];
    float b = feat[(size_t)dst*256 + j];
    dot += a*b; nj += a*a; ni += b*b;
  }
  for (int off = 32; off > 0; off >>= 1) {
    dot += __shfl_down(dot, off);
    nj  += __shfl_down(nj,  off);
    ni  += __shfl_down(ni,  off);
  }
  if (lane == 0) {
    float denom = fmaxf(sqrtf(nj)*sqrtf(ni), 1e-6f);
    atomicAdd(&nsum[dst], dot/denom);
    atomicAdd(&ncnt[dst], 1.f);
  }
}

__global__ void cos_loss_k(const float* __restrict__ nsum, const float* __restrict__ ncnt,
                           float* __restrict__ cosloss)
{
  int g = threadIdx.x;
  float v = 0.f;
  if (g < 48) {
    float gm = 0.f;
    for (int i = 0; i < 4; ++i) {
      int nd = 4*g + i;
      gm += nsum[nd] / fmaxf(ncnt[nd], 1.f);
    }
    gm *= 0.25f;
    v = (gm - 1.f)*(gm - 1.f);
  }
  for (int off = 32; off > 0; off >>= 1) v += __shfl_down(v, off);
  if (g == 0) cosloss[0] = v;
}

__global__ void pd_out(const float* __restrict__ s_cat, const float* __restrict__ p_cat,
                       const int* __restrict__ support_y, const int* __restrict__ query_y,
                       float* __restrict__ ce, float* __restrict__ correct)
{
  const int q = blockIdx.x;
  const int tid = threadIdx.x, lane = tid & 63, wid = tid >> 6;
  __shared__ float sP[48];
  __shared__ float sOut[24];
  float pv[4];
  #pragma unroll
  for (int j = 0; j < 4; ++j) pv[j] = p_cat[(size_t)q*256 + lane + 64*j];
  for (int s = wid*12; s < wid*12 + 12; ++s) {
    float d2 = 0.f;
    #pragma unroll
    for (int j = 0; j < 4; ++j) {
      float diff = pv[j] - s_cat[(size_t)s*256 + lane + 64*j];
      d2 += diff*diff;
    }
    for (int off = 32; off > 0; off >>= 1) d2 += __shfl_down(d2, off);
    if (lane == 0) sP[s] = expf(-d2);
  }
  __syncthreads();
  if (tid < 24) {
    int c = tid; float sum = 0.f; int cnt = 0;
    for (int s = 0; s < 48; ++s)
      if (support_y[s] == c) { sum += sP[s]; ++cnt; }
    sOut[c] = sum / fmaxf((float)cnt, 1.f);
  }
  __syncthreads();
  if (tid == 0) {
    float m = sOut[0]; int am = 0;
    for (int c = 1; c < 24; ++c) if (sOut[c] > m) { m = sOut[c]; am = c; }
    float lse = 0.f;
    for (int c = 0; c < 24; ++c) lse += expf(sOut[c] - m);
    lse = m + logf(lse);
    int y = query_y[q];
    ce[q] = lse - sOut[y];
    correct[q] = (am == y) ? 1.f : 0.f;
  }
}

__global__ void final_k(const float* __restrict__ ce, const float* __restrict__ correct,
                        const float* __restrict__ cosloss, float* __restrict__ out)
{
  if (threadIdx.x == 0) {
    float s = 0.f, a = 0.f;
    for (int qq = 0; qq < 24; ++qq) { s += ce[qq]; a += correct[qq]; }
    float atten = ce[5];
    float rest  = (s - atten) / 23.f;
    float cl = cosloss[0];
    out[0] = atten + rest + cl;
    out[1] = a;
    out[2] = cl;
    out[3] = atten;
    out[4] = rest;
  }
}

// ---------------------------------------------------------------------------
extern "C" void kernel_launch(void* const* d_in, const int* in_sizes, int n_in,
                              void* d_out, int out_size, void* d_ws, size_t ws_size,
                              hipStream_t stream)
{
  const float* support_x = (const float*)d_in[0];
  const float* query_x   = (const float*)d_in[1];
  const int*   s_ei      = (const int*)d_in[2];
  const int*   s_y       = (const int*)d_in[6];
  const int*   q_y       = (const int*)d_in[7];
  const float* w1 = (const float*)d_in[8];
  const float* g1 = (const float*)d_in[9];
  const float* b1 = (const float*)d_in[10];
  const float* w2 = (const float*)d_in[11];
  const float* g2 = (const float*)d_in[12];
  const float* b2 = (const float*)d_in[13];
  const float* wr = (const float*)d_in[14];
  const float* gr = (const float*)d_in[15];
  const float* br = (const float*)d_in[16];
  (void)in_sizes; (void)n_in; (void)out_size;

  char* ws = (char*)d_ws;
  size_t off = 0;
  auto alloc = [&](size_t bytes) -> char* {
    char* p = ws + off;
    off = (off + bytes + 255) & ~(size_t)255;
    return p;
  };
  float*  actA  = (float*)alloc((size_t)288*32*64*64*4);   // 151 MB ping
  float*  actB  = (float*)alloc((size_t)288*64*32*32*4);   // 75.5 MB pong
  double* stats = (double*)alloc(2*64*2*8);
  float*  scl   = (float*)alloc(2*64*4);
  float*  shf   = (float*)alloc(2*64*4);
  float*  s_cat = (float*)alloc(48*256*4);
  float*  p_cat = (float*)alloc(24*256*4);
  float*  nsum  = (float*)alloc(192*4);
  float*  ncnt  = (float*)alloc(192*4);
  float*  cosl  = (float*)alloc(256);
  float*  ce    = (float*)alloc(24*4);
  float*  corr  = (float*)alloc(24*4);
  if (off > ws_size) return;

  const int NS = 192;
  const int BIG = 1 << 30;
  const size_t statsB = 2*64*2*8;

  // ---- L1: 3->32 @128, pool->64, out actA
  hipMemsetAsync(stats, 0, statsB, stream);
  conv_tiled<3,32,128,32,16,false><<<dim3(16,2,288),256,0,stream>>>(
      support_x, query_x, 192, w1, nullptr, nullptr, stats, nullptr, NS);
  bn_finalize<<<1,128,0,stream>>>(stats, g1, b1, scl, shf, 32,
      192.0*128*128, 96.0*128*128);
  conv_tiled<3,32,128,32,16,true><<<dim3(16,2,288),256,0,stream>>>(
      support_x, query_x, 192, w1, scl, shf, nullptr, actA, NS);

  // ---- L2: 32->64 @64, pool->32, out actB
  hipMemsetAsync(stats, 0, statsB, stream);
  conv_tiled<32,64,64,32,16,false><<<dim3(4,4,288),256,0,stream>>>(
      actA, actA, BIG, w2, nullptr, nullptr, stats, nullptr, NS);
  bn_finalize<<<1,128,0,stream>>>(stats, g2, b2, scl, shf, 64,
      192.0*64*64, 96.0*64*64);
  conv_tiled<32,64,64,32,16,true><<<dim3(4,4,288),256,0,stream>>>(
      actA, actA, BIG, w2, scl, shf, nullptr, actB, NS);

  // ---- L3: 64->64 @32, pool->16, out actA (w_rest[0])
  hipMemsetAsync(stats, 0, statsB, stream);
  conv_tiled<64,64,32,32,16,false><<<dim3(1,4,288),256,0,stream>>>(
      actB, actB, BIG, wr + 0*36864, nullptr, nullptr, stats, nullptr, NS);
  bn_finalize<<<1,128,0,stream>>>(stats, gr + 0*64, br + 0*64, scl, shf, 64,
      192.0*32*32, 96.0*32*32);
  conv_tiled<64,64,32,32,16,true><<<dim3(1,4,288),256,0,stream>>>(
      actB, actB, BIG, wr + 0*36864, scl, shf, nullptr, actA, NS);

  // ---- L4: 64->64 @16, pool->8, out actB (w_rest[1]); OCG=4 for occupancy
  hipMemsetAsync(stats, 0, statsB, stream);
  conv_tiled<64,64,16,16,4,false><<<dim3(1,16,288),64,0,stream>>>(
      actA, actA, BIG, wr + 1*36864, nullptr, nullptr, stats, nullptr, NS);
  bn_finalize<<<1,128,0,stream>>>(stats, gr + 1*64, br + 1*64, scl, shf, 64,
      192.0*16*16, 96.0*16*16);
  conv_tiled<64,64,16,16,4,true><<<dim3(1,16,288),64,0,stream>>>(
      actA, actA, BIG, wr + 1*36864, scl, shf, nullptr, actB, NS);

  // ---- L5: 64->64 @8, pool->4, out actA (w_rest[2])
  hipMemsetAsync(stats, 0, statsB, stream);
  conv_small<8,false><<<288,256,0,stream>>>(
      actB, wr + 2*36864, nullptr, nullptr, stats, nullptr, NS);
  bn_finalize<<<1,128,0,stream>>>(stats, gr + 2*64, br + 2*64, scl, shf, 64,
      192.0*8*8, 96.0*8*8);
  conv_small<8,true><<<288,256,0,stream>>>(
      actB, wr + 2*36864, scl, shf, nullptr, actA, NS);

  // ---- L6: 64->64 @4, pool->2, out actB = feat [288,256] (w_rest[3])
  hipMemsetAsync(stats, 0, statsB, stream);
  conv_small<4,false><<<288,256,0,stream>>>(
      actA, wr + 3*36864, nullptr, nullptr, stats, nullptr, NS);
  bn_finalize<<<1,128,0,stream>>>(stats, gr + 3*64, br + 3*64, scl, shf, 64,
      192.0*4*4, 96.0*4*4);
  conv_small<4,true><<<288,256,0,stream>>>(
      actA, wr + 3*36864, scl, shf, nullptr, actB, NS);

  // ---- head
  float* feat = actB;
  graph_means<<<72,256,0,stream>>>(feat, s_cat, p_cat);
  hipMemsetAsync(nsum, 0, 192*4, stream);
  hipMemsetAsync(ncnt, 0, 192*4, stream);
  edge_cos<<<768,64,0,stream>>>(feat, s_ei, nsum, ncnt, 768);
  cos_loss_k<<<1,64,0,stream>>>(nsum, ncnt, cosl);
  pd_out<<<24,256,0,stream>>>(s_cat, p_cat, s_y, q_y, ce, corr);
  final_k<<<1,64,0,stream>>>(ce, corr, cosl, (float*)d_out);
}